// Round 3
// baseline (531.939 us; speedup 1.0000x reference)
//
#include <hip/hip_runtime.h>
#include <math.h>

#define DIM 1024
#define SEQ 2048
#define BATCH 4
#define ROWS (BATCH*SEQ)        // 8192
#define CHUNKS 64
#define CLEN (SEQ/CHUNKS)       // 32
#define LN_EPS 1e-5f

typedef unsigned short ushort_t;
typedef __attribute__((ext_vector_type(8))) short bf16x8;
typedef __attribute__((ext_vector_type(4))) float f32x4;

// fp32 -> bf16 round-to-nearest-even
__device__ inline ushort_t f2bf(float f) {
    union { float f; unsigned u; } v; v.f = f;
    unsigned r = v.u + 0x7FFFu + ((v.u >> 16) & 1u);
    return (ushort_t)(r >> 16);
}
__device__ inline float bf_lo(unsigned p) { return __uint_as_float(p << 16); }
__device__ inline float bf_hi(unsigned p) { return __uint_as_float(p & 0xFFFF0000u); }

// ---------------------------------------------------------------------------
// fp32 -> bf16 conversion, 8 elements/thread (count must be multiple of 2048)
// ---------------------------------------------------------------------------
__global__ __launch_bounds__(256)
void f32_to_bf16_k(const float* __restrict__ in, ushort_t* __restrict__ out)
{
    size_t i = ((size_t)blockIdx.x * 256 + threadIdx.x) * 8;
    float4 a = *(const float4*)(in + i);
    float4 b = *(const float4*)(in + i + 4);
    ushort4 lo, hi;
    lo.x = f2bf(a.x); lo.y = f2bf(a.y); lo.z = f2bf(a.z); lo.w = f2bf(a.w);
    hi.x = f2bf(b.x); hi.y = f2bf(b.y); hi.z = f2bf(b.z); hi.w = f2bf(b.w);
    *(ushort4*)(out + i) = lo;
    *(ushort4*)(out + i + 4) = hi;
}

// ---------------------------------------------------------------------------
// bf16 MFMA GEMM (NT): C[m,n] = sum_k A[m,k]*W[n,k] + bias[n], fused epilogues
// MODE 0: bf16 out                      (key, query)
// MODE 1: f32 out                       (value)
// MODE 2: phase-KV: kplin=acc+bias; kp=bp+kplin*ms;
//         write packed bf16 {value*cos(kp), value*sin(kp)}   (aux0=value, aux1=bp)
// MODE 3: qp = bp + (acc+bias)*ms, f32 out                    (aux1=bp)
// MODE 4: f32 out + residual aux0
// m97 structure: 128x128 tile, BK=32, 4 waves, global_load_lds w=16.
// ---------------------------------------------------------------------------
template<int MODE>
__global__ __launch_bounds__(256)
void gemm_bf16_nt(const ushort_t* __restrict__ A, const ushort_t* __restrict__ W,
                  const float* __restrict__ bias, const float* __restrict__ aux0,
                  const float* __restrict__ aux1, const float* __restrict__ ms_p,
                  void* __restrict__ Cout, int M, int N, int K)
{
    __shared__ ushort_t As[128 * 32];
    __shared__ ushort_t Bs[128 * 32];
    const int bm = blockIdx.x * 128;
    const int bn = blockIdx.y * 128;
    const int t = threadIdx.x;
    const int lane = t & 63;
    const int w = t >> 6;
    const int wr = w >> 1;
    const int wc = w & 1;

    f32x4 acc[4][4] = {};

    const int fr = lane & 15;
    const int kc = (lane >> 4) * 8;

    for (int k0 = 0; k0 < K; k0 += 32) {
        #pragma unroll
        for (int i = 0; i < 2; ++i) {
            int c = t + i * 256;
            int row = c >> 2;
            int col = (c & 3) * 8;
            const ushort_t* ga = A + (size_t)(bm + row) * K + k0 + col;
            __builtin_amdgcn_global_load_lds(
                (const __attribute__((address_space(1))) void*)ga,
                (__attribute__((address_space(3))) void*)(As + (size_t)c * 8),
                16, 0, 0);
            const ushort_t* gb = W + (size_t)(bn + row) * K + k0 + col;
            __builtin_amdgcn_global_load_lds(
                (const __attribute__((address_space(1))) void*)gb,
                (__attribute__((address_space(3))) void*)(Bs + (size_t)c * 8),
                16, 0, 0);
        }
        __syncthreads();

        bf16x8 af[4], bw[4];
        #pragma unroll
        for (int m2 = 0; m2 < 4; ++m2)
            af[m2] = *(const bf16x8*)(As + (wr * 64 + m2 * 16 + fr) * 32 + kc);
        #pragma unroll
        for (int n2 = 0; n2 < 4; ++n2)
            bw[n2] = *(const bf16x8*)(Bs + (wc * 64 + n2 * 16 + fr) * 32 + kc);
        #pragma unroll
        for (int m2 = 0; m2 < 4; ++m2)
            #pragma unroll
            for (int n2 = 0; n2 < 4; ++n2)
                acc[m2][n2] = __builtin_amdgcn_mfma_f32_16x16x32_bf16(
                    af[m2], bw[n2], acc[m2][n2], 0, 0, 0);
        __syncthreads();
    }

    const float msv = (MODE == 2 || MODE == 3) ? ms_p[0] : 0.0f;
    const int fc = lane & 15;
    const int r0 = (lane >> 4) * 4;
    #pragma unroll
    for (int m2 = 0; m2 < 4; ++m2) {
        #pragma unroll
        for (int n2 = 0; n2 < 4; ++n2) {
            int col = bn + wc * 64 + n2 * 16 + fc;
            float bv = bias[col];
            #pragma unroll
            for (int r = 0; r < 4; ++r) {
                int row = bm + wr * 64 + m2 * 16 + r0 + r;
                size_t idx = (size_t)row * N + col;
                float v = acc[m2][n2][r] + bv;
                if (MODE == 0) {
                    ((ushort_t*)Cout)[idx] = f2bf(v);
                } else if (MODE == 1) {
                    ((float*)Cout)[idx] = v;
                } else if (MODE == 2) {
                    float val = aux0[idx];
                    float bph = aux1[(size_t)(row & (SEQ - 1)) * N + col];
                    float kp = bph + v * msv;
                    float sk, ck;
                    sincosf(kp, &sk, &ck);
                    unsigned pk = (unsigned)f2bf(val * ck) |
                                  ((unsigned)f2bf(val * sk) << 16);
                    ((unsigned*)Cout)[idx] = pk;
                } else if (MODE == 3) {
                    float bph = aux1[(size_t)(row & (SEQ - 1)) * N + col];
                    ((float*)Cout)[idx] = bph + v * msv;
                } else {  // MODE 4
                    ((float*)Cout)[idx] = v + aux0[idx];
                }
            }
        }
    }
}

// ---------------------------------------------------------------------------
// Scan pass 1: per (b, chunk, d) partial sums of packed (a,bi) over CLEN.
// ---------------------------------------------------------------------------
__global__ __launch_bounds__(256)
void scan_pass1(const unsigned* __restrict__ ab,
                float* __restrict__ sumr, float* __restrict__ sumi)
{
    int gid = blockIdx.x * 256 + threadIdx.x;   // BATCH*CHUNKS*DIM = 262144
    int d = gid & (DIM - 1);
    int c = (gid >> 10) & (CHUNKS - 1);
    int b = gid >> 16;
    size_t base = ((size_t)(b * SEQ + c * CLEN)) * DIM + d;
    float sr = 0.f, si = 0.f;
    #pragma unroll 4
    for (int s = 0; s < CLEN; ++s) {
        unsigned p = ab[base + (size_t)s * DIM];
        sr += bf_lo(p);
        si += bf_hi(p);
    }
    sumr[gid] = sr;
    sumi[gid] = si;
}

// ---------------------------------------------------------------------------
// Scan pass 2: exclusive prefix over CHUNKS chunk-sums per (b,d).
// One wave per (b,d); lane = chunk index; in-wave shfl_up prefix scan.
// ---------------------------------------------------------------------------
__global__ __launch_bounds__(256)
void scan_pass2(float* __restrict__ sumr, float* __restrict__ sumi)
{
    int wid  = (blockIdx.x * 256 + threadIdx.x) >> 6;   // 0..4095 = (b,d)
    int lane = threadIdx.x & 63;
    int b = wid >> 10;
    int d = wid & (DIM - 1);
    int idx = (b * CHUNKS + lane) * DIM + d;
    float r  = sumr[idx], im = sumi[idx];
    float r0 = r, i0 = im;
    #pragma unroll
    for (int o = 1; o < 64; o <<= 1) {
        float tr = __shfl_up(r, o);
        float ti = __shfl_up(im, o);
        if (lane >= o) { r += tr; im += ti; }
    }
    sumr[idx] = r - r0;    // exclusive prefix
    sumi[idx] = im - i0;
}

// ---------------------------------------------------------------------------
// Scan pass 3: running inclusive sums + retrieved, in place over qp buffer.
// ---------------------------------------------------------------------------
__global__ __launch_bounds__(256)
void scan_pass3(const unsigned* __restrict__ ab, float* __restrict__ qp_retr,
                const float* __restrict__ sumr, const float* __restrict__ sumi)
{
    int gid = blockIdx.x * 256 + threadIdx.x;   // BATCH*CHUNKS*DIM
    int d = gid & (DIM - 1);
    int c = (gid >> 10) & (CHUNKS - 1);
    int b = gid >> 16;
    size_t base = ((size_t)(b * SEQ + c * CLEN)) * DIM + d;
    float rr = sumr[gid], ri = sumi[gid];
    const float inv_sqrt_dim = 0.03125f;   // 1/sqrt(1024)
    for (int s = 0; s < CLEN; ++s) {
        size_t idx = base + (size_t)s * DIM;
        unsigned p = ab[idx];
        rr += bf_lo(p);
        ri += bf_hi(p);
        float q = qp_retr[idx];
        float sq, cq;
        sincosf(q, &sq, &cq);
        qp_retr[idx] = (rr * cq + ri * sq) * inv_sqrt_dim;
    }
}

// ---------------------------------------------------------------------------
// LayerNorm per row (population variance) -> bf16 output for final GEMM.
// ---------------------------------------------------------------------------
__global__ __launch_bounds__(256)
void layernorm_bf16(const float* __restrict__ in, const float* __restrict__ g,
                    const float* __restrict__ beta, ushort_t* __restrict__ out)
{
    int row = blockIdx.x;
    int t = threadIdx.x;
    const float4 v = ((const float4*)(in + (size_t)row * DIM))[t];
    float s  = v.x + v.y + v.z + v.w;
    float ss = v.x*v.x + v.y*v.y + v.z*v.z + v.w*v.w;
    #pragma unroll
    for (int o = 32; o >= 1; o >>= 1) {
        s  += __shfl_down(s, o);
        ss += __shfl_down(ss, o);
    }
    __shared__ float red[8];
    int wid = t >> 6, lane = t & 63;
    if (lane == 0) { red[wid] = s; red[wid + 4] = ss; }
    __syncthreads();
    if (t == 0) {
        float S  = red[0] + red[1] + red[2] + red[3];
        float SS = red[4] + red[5] + red[6] + red[7];
        red[0] = S; red[4] = SS;
    }
    __syncthreads();
    float mu  = red[0] * (1.0f / DIM);
    float var = red[4] * (1.0f / DIM) - mu * mu;
    float rstd = rsqrtf(var + LN_EPS);
    float4 gv = ((const float4*)g)[t];
    float4 bv = ((const float4*)beta)[t];
    ushort4 o;
    o.x = f2bf((v.x - mu) * rstd * gv.x + bv.x);
    o.y = f2bf((v.y - mu) * rstd * gv.y + bv.y);
    o.z = f2bf((v.z - mu) * rstd * gv.z + bv.z);
    o.w = f2bf((v.w - mu) * rstd * gv.w + bv.w);
    ((ushort4*)(out + (size_t)row * DIM))[t] = o;
}

// ---------------------------------------------------------------------------
extern "C" void kernel_launch(void* const* d_in, const int* in_sizes, int n_in,
                              void* d_out, int out_size, void* d_ws, size_t ws_size,
                              hipStream_t stream)
{
    const float* x   = (const float*)d_in[0];
    const float* bp  = (const float*)d_in[1];
    const float* Wk  = (const float*)d_in[2];
    const float* bk  = (const float*)d_in[3];
    const float* Wv  = (const float*)d_in[4];
    const float* bv  = (const float*)d_in[5];
    const float* Wq  = (const float*)d_in[6];
    const float* bq  = (const float*)d_in[7];
    const float* Wkm = (const float*)d_in[8];
    const float* bkm = (const float*)d_in[9];
    const float* Wqm = (const float*)d_in[10];
    const float* bqm = (const float*)d_in[11];
    const float* ms  = (const float*)d_in[12];
    const float* lng = (const float*)d_in[13];
    const float* lnb = (const float*)d_in[14];
    const float* Wo  = (const float*)d_in[15];
    const float* bo  = (const float*)d_in[16];
    float* out = (float*)d_out;

    const size_t NE = (size_t)ROWS * DIM;            // 8.4M
    const size_t WN = (size_t)DIM * DIM;             // 1M

    unsigned* ab   = (unsigned*)d_ws;                // packed bf16 (a,bi), NE u32
    float* vqbuf   = (float*)(ab + NE);              // value -> qp -> retrieved
    ushort_t* xbf  = (ushort_t*)(vqbuf + NE);        // bf16 x
    ushort_t* actbf = xbf + NE;                      // key_bf / query_bf / normed_bf
    ushort_t* wbf  = actbf + NE;                     // 6 bf16 weights
    float* sumr    = (float*)(wbf + 6 * WN);         // BATCH*CHUNKS*DIM
    float* sumi    = sumr + (size_t)BATCH * CHUNKS * DIM;

    ushort_t* wk_b  = wbf;
    ushort_t* wkm_b = wbf + WN;
    ushort_t* wq_b  = wbf + 2 * WN;
    ushort_t* wqm_b = wbf + 3 * WN;
    ushort_t* wv_b  = wbf + 4 * WN;
    ushort_t* wo_b  = wbf + 5 * WN;

    // --- convert inputs to bf16 ---
    f32_to_bf16_k<<<(int)(NE / 2048), 256, 0, stream>>>(x, xbf);
    f32_to_bf16_k<<<(int)(WN / 2048), 256, 0, stream>>>(Wk,  wk_b);
    f32_to_bf16_k<<<(int)(WN / 2048), 256, 0, stream>>>(Wkm, wkm_b);
    f32_to_bf16_k<<<(int)(WN / 2048), 256, 0, stream>>>(Wq,  wq_b);
    f32_to_bf16_k<<<(int)(WN / 2048), 256, 0, stream>>>(Wqm, wqm_b);
    f32_to_bf16_k<<<(int)(WN / 2048), 256, 0, stream>>>(Wv,  wv_b);
    f32_to_bf16_k<<<(int)(WN / 2048), 256, 0, stream>>>(Wo,  wo_b);

    dim3 gg(ROWS / 128, DIM / 128);   // 64 x 8 = 512 workgroups

    // value = f32(x @ Wv^T + bv)
    gemm_bf16_nt<1><<<gg, 256, 0, stream>>>(xbf, wv_b, bv, nullptr, nullptr, nullptr,
                                            vqbuf, ROWS, DIM, DIM);
    // key_bf = bf16(x @ Wk^T + bk)
    gemm_bf16_nt<0><<<gg, 256, 0, stream>>>(xbf, wk_b, bk, nullptr, nullptr, nullptr,
                                            actbf, ROWS, DIM, DIM);
    // fused: kplin -> kp -> packed (a,bi)
    gemm_bf16_nt<2><<<gg, 256, 0, stream>>>(actbf, wkm_b, bkm, vqbuf, bp, ms,
                                            ab, ROWS, DIM, DIM);
    // query_bf = bf16(x @ Wq^T + bq)   (value consumed; actbf reused)
    gemm_bf16_nt<0><<<gg, 256, 0, stream>>>(xbf, wq_b, bq, nullptr, nullptr, nullptr,
                                            actbf, ROWS, DIM, DIM);
    // fused: qplin -> qp (f32, overwrites value buffer)
    gemm_bf16_nt<3><<<gg, 256, 0, stream>>>(actbf, wqm_b, bqm, nullptr, bp, ms,
                                            vqbuf, ROWS, DIM, DIM);

    // chunked inclusive scan + retrieved (in place over qp)
    scan_pass1<<<(BATCH * CHUNKS * DIM) / 256, 256, 0, stream>>>(ab, sumr, sumi);
    scan_pass2<<<(BATCH * DIM * 64) / 256, 256, 0, stream>>>(sumr, sumi);
    scan_pass3<<<(BATCH * CHUNKS * DIM) / 256, 256, 0, stream>>>(ab, vqbuf, sumr, sumi);

    // layernorm: retrieved -> normed_bf
    layernorm_bf16<<<ROWS, 256, 0, stream>>>(vqbuf, lng, lnb, actbf);

    // out = x + normed_bf @ Wo^T + bo
    gemm_bf16_nt<4><<<gg, 256, 0, stream>>>(actbf, wo_b, bo, x, nullptr, nullptr,
                                            out, ROWS, DIM, DIM);
}

// Round 4
// 256.340 us; speedup vs baseline: 2.0751x; 2.0751x over previous
//
#include <hip/hip_runtime.h>
#include <math.h>

#define DIM 1024
#define SEQ 2048
#define BATCH 4
#define ROWS (BATCH*SEQ)        // 8192
#define CHUNKS 64
#define CLEN (SEQ/CHUNKS)       // 32
#define LN_EPS 1e-5f

typedef unsigned short ushort_t;
typedef __attribute__((ext_vector_type(8))) short bf16x8;
typedef __attribute__((ext_vector_type(4))) float f32x4;

// fp32 -> bf16 round-to-nearest-even
__device__ inline ushort_t f2bf(float f) {
    union { float f; unsigned u; } v; v.f = f;
    unsigned r = v.u + 0x7FFFu + ((v.u >> 16) & 1u);
    return (ushort_t)(r >> 16);
}
__device__ inline float bf2f(ushort_t u) { return __uint_as_float((unsigned)u << 16); }
__device__ inline float bf_lo(unsigned p) { return __uint_as_float(p << 16); }
__device__ inline float bf_hi(unsigned p) { return __uint_as_float(p & 0xFFFF0000u); }

// ---------------------------------------------------------------------------
// fp32 -> bf16, 8 elems/thread (count multiple of 2048)
// ---------------------------------------------------------------------------
__global__ __launch_bounds__(256)
void f32_to_bf16_k(const float* __restrict__ in, ushort_t* __restrict__ out)
{
    size_t i = ((size_t)blockIdx.x * 256 + threadIdx.x) * 8;
    float4 a = *(const float4*)(in + i);
    float4 b = *(const float4*)(in + i + 4);
    ushort4 lo, hi;
    lo.x = f2bf(a.x); lo.y = f2bf(a.y); lo.z = f2bf(a.z); lo.w = f2bf(a.w);
    hi.x = f2bf(b.x); hi.y = f2bf(b.y); hi.z = f2bf(b.z); hi.w = f2bf(b.w);
    *(ushort4*)(out + i) = lo;
    *(ushort4*)(out + i + 4) = hi;
}

// ---------------------------------------------------------------------------
// fp32 -> bf16 TRANSPOSED (1024x1024): out[c][d] = bf16(in[d][c])
// ---------------------------------------------------------------------------
__global__ __launch_bounds__(256)
void f32_to_bf16_T_k(const float* __restrict__ in, ushort_t* __restrict__ out)
{
    __shared__ ushort_t tile[32][33];
    const int bx = blockIdx.x, by = blockIdx.y;
    const int tx = threadIdx.x & 31, ty = threadIdx.x >> 5;   // 32x8
    #pragma unroll
    for (int j = 0; j < 4; ++j) {
        int r = by * 32 + ty + j * 8;
        tile[ty + j * 8][tx] = f2bf(in[(size_t)r * DIM + bx * 32 + tx]);
    }
    __syncthreads();
    #pragma unroll
    for (int j = 0; j < 4; ++j) {
        int r = bx * 32 + ty + j * 8;
        out[(size_t)r * DIM + by * 32 + tx] = tile[tx][ty + j * 8];
    }
}

// ---------------------------------------------------------------------------
// bc[e] = sum_d Wm[e,d] * b_in[d] + b_out[e]   (fp32, 1 wave/row, grid 256)
// ---------------------------------------------------------------------------
__global__ __launch_bounds__(256)
void matvec_bias_k(const float* __restrict__ Wm, const float* __restrict__ b_in,
                   const float* __restrict__ b_out, float* __restrict__ bc)
{
    int e = blockIdx.x * 4 + (threadIdx.x >> 6);
    int l = threadIdx.x & 63;
    float s = 0.f;
    #pragma unroll
    for (int j = 0; j < DIM / 64; ++j)
        s += Wm[(size_t)e * DIM + l + j * 64] * b_in[l + j * 64];
    #pragma unroll
    for (int o = 32; o >= 1; o >>= 1) s += __shfl_down(s, o);
    if (l == 0) bc[e] = s + b_out[e];
}

// ---------------------------------------------------------------------------
// bf16 MFMA GEMM (NT): C[m,n] = sum_k A[m,k]*W[n,k] [+ bias] [+ resid]
// MODE 0: bf16 out, +bias          (value)
// MODE 4: f32 out, +bias, +resid   (final output)
// MODE 5: bf16 out, no bias        (kplin/qplin/weight-combine)
// m97 structure: 128x128 tile, BK=32, 4 waves, global_load_lds w=16.
// ---------------------------------------------------------------------------
template<int MODE>
__global__ __launch_bounds__(256)
void gemm_bf16_nt(const ushort_t* __restrict__ A, const ushort_t* __restrict__ W,
                  const float* __restrict__ bias, const float* __restrict__ resid,
                  void* __restrict__ Cout, int M, int N, int K)
{
    __shared__ ushort_t As[128 * 32];
    __shared__ ushort_t Bs[128 * 32];
    const int bm = blockIdx.x * 128;
    const int bn = blockIdx.y * 128;
    const int t = threadIdx.x;
    const int lane = t & 63;
    const int w = t >> 6;
    const int wr = w >> 1;
    const int wc = w & 1;

    f32x4 acc[4][4] = {};

    const int fr = lane & 15;
    const int kc = (lane >> 4) * 8;

    for (int k0 = 0; k0 < K; k0 += 32) {
        #pragma unroll
        for (int i = 0; i < 2; ++i) {
            int c = t + i * 256;
            int row = c >> 2;
            int col = (c & 3) * 8;
            const ushort_t* ga = A + (size_t)(bm + row) * K + k0 + col;
            __builtin_amdgcn_global_load_lds(
                (const __attribute__((address_space(1))) void*)ga,
                (__attribute__((address_space(3))) void*)(As + (size_t)c * 8),
                16, 0, 0);
            const ushort_t* gb = W + (size_t)(bn + row) * K + k0 + col;
            __builtin_amdgcn_global_load_lds(
                (const __attribute__((address_space(1))) void*)gb,
                (__attribute__((address_space(3))) void*)(Bs + (size_t)c * 8),
                16, 0, 0);
        }
        __syncthreads();

        bf16x8 af[4], bw[4];
        #pragma unroll
        for (int m2 = 0; m2 < 4; ++m2)
            af[m2] = *(const bf16x8*)(As + (wr * 64 + m2 * 16 + fr) * 32 + kc);
        #pragma unroll
        for (int n2 = 0; n2 < 4; ++n2)
            bw[n2] = *(const bf16x8*)(Bs + (wc * 64 + n2 * 16 + fr) * 32 + kc);
        #pragma unroll
        for (int m2 = 0; m2 < 4; ++m2)
            #pragma unroll
            for (int n2 = 0; n2 < 4; ++n2)
                acc[m2][n2] = __builtin_amdgcn_mfma_f32_16x16x32_bf16(
                    af[m2], bw[n2], acc[m2][n2], 0, 0, 0);
        __syncthreads();
    }

    const int fc = lane & 15;
    const int r0 = (lane >> 4) * 4;
    #pragma unroll
    for (int m2 = 0; m2 < 4; ++m2) {
        #pragma unroll
        for (int n2 = 0; n2 < 4; ++n2) {
            int col = bn + wc * 64 + n2 * 16 + fc;
            float bv = (MODE == 5) ? 0.0f : bias[col];
            #pragma unroll
            for (int r = 0; r < 4; ++r) {
                int row = bm + wr * 64 + m2 * 16 + r0 + r;
                size_t idx = (size_t)row * N + col;
                float v = acc[m2][n2][r] + bv;
                if (MODE == 4) {
                    ((float*)Cout)[idx] = v + resid[idx];
                } else {
                    ((ushort_t*)Cout)[idx] = f2bf(v);
                }
            }
        }
    }
}

// ---------------------------------------------------------------------------
// Phase elementwise (coalesced, 4 elems/thread):
//   kp = bp + (kplin_nb + bck[d]) * ms
//   ab = packed bf16 { value*cos(kp), value*sin(kp) }
// ---------------------------------------------------------------------------
__global__ __launch_bounds__(256)
void phase_ab_k(const ushort_t* __restrict__ vbf, const ushort_t* __restrict__ kbf,
                const float* __restrict__ bp, const float* __restrict__ bck,
                const float* __restrict__ ms_p, unsigned* __restrict__ ab)
{
    size_t i = ((size_t)blockIdx.x * 256 + threadIdx.x) * 4;
    const float ms = ms_p[0];
    int d  = (int)(i & (DIM - 1));
    int sd = (int)(i & ((size_t)SEQ * DIM - 1));
    ushort4 v4 = *(const ushort4*)(vbf + i);
    ushort4 k4 = *(const ushort4*)(kbf + i);
    float4 bp4 = *(const float4*)(bp + sd);
    float4 bc4 = *(const float4*)(bck + d);
    uint4 o;
    {
        float v = bf2f(v4.x), kp = bp4.x + (bf2f(k4.x) + bc4.x) * ms, s, c;
        sincosf(kp, &s, &c);
        o.x = (unsigned)f2bf(v * c) | ((unsigned)f2bf(v * s) << 16);
    }
    {
        float v = bf2f(v4.y), kp = bp4.y + (bf2f(k4.y) + bc4.y) * ms, s, c;
        sincosf(kp, &s, &c);
        o.y = (unsigned)f2bf(v * c) | ((unsigned)f2bf(v * s) << 16);
    }
    {
        float v = bf2f(v4.z), kp = bp4.z + (bf2f(k4.z) + bc4.z) * ms, s, c;
        sincosf(kp, &s, &c);
        o.z = (unsigned)f2bf(v * c) | ((unsigned)f2bf(v * s) << 16);
    }
    {
        float v = bf2f(v4.w), kp = bp4.w + (bf2f(k4.w) + bc4.w) * ms, s, c;
        sincosf(kp, &s, &c);
        o.w = (unsigned)f2bf(v * c) | ((unsigned)f2bf(v * s) << 16);
    }
    *(uint4*)(ab + i) = o;
}

// ---------------------------------------------------------------------------
// Scan pass 1: per (b, chunk, d) partial sums of packed (a,bi) over CLEN.
// ---------------------------------------------------------------------------
__global__ __launch_bounds__(256)
void scan_pass1(const unsigned* __restrict__ ab,
                float* __restrict__ sumr, float* __restrict__ sumi)
{
    int gid = blockIdx.x * 256 + threadIdx.x;   // BATCH*CHUNKS*DIM = 262144
    int d = gid & (DIM - 1);
    int c = (gid >> 10) & (CHUNKS - 1);
    int b = gid >> 16;
    size_t base = ((size_t)(b * SEQ + c * CLEN)) * DIM + d;
    float sr = 0.f, si = 0.f;
    #pragma unroll 4
    for (int s = 0; s < CLEN; ++s) {
        unsigned p = ab[base + (size_t)s * DIM];
        sr += bf_lo(p);
        si += bf_hi(p);
    }
    sumr[gid] = sr;
    sumi[gid] = si;
}

// ---------------------------------------------------------------------------
// Scan pass 2: exclusive prefix over CHUNKS(=64) chunk-sums, 1 wave/(b,d).
// ---------------------------------------------------------------------------
__global__ __launch_bounds__(256)
void scan_pass2(float* __restrict__ sumr, float* __restrict__ sumi)
{
    int wid  = (blockIdx.x * 256 + threadIdx.x) >> 6;   // 0..4095 = (b,d)
    int lane = threadIdx.x & 63;
    int b = wid >> 10;
    int d = wid & (DIM - 1);
    int idx = (b * CHUNKS + lane) * DIM + d;
    float r  = sumr[idx], im = sumi[idx];
    float r0 = r, i0 = im;
    #pragma unroll
    for (int o = 1; o < 64; o <<= 1) {
        float tr = __shfl_up(r, o);
        float ti = __shfl_up(im, o);
        if (lane >= o) { r += tr; im += ti; }
    }
    sumr[idx] = r - r0;    // exclusive prefix
    sumi[idx] = im - i0;
}

// ---------------------------------------------------------------------------
// Scan pass 3: running inclusive sums; qp recomputed from bp + qplin;
// retrieved written bf16.
// ---------------------------------------------------------------------------
__global__ __launch_bounds__(256)
void scan_pass3(const unsigned* __restrict__ ab, const ushort_t* __restrict__ qbf,
                const float* __restrict__ bp, const float* __restrict__ bcq,
                const float* __restrict__ ms_p,
                const float* __restrict__ sumr, const float* __restrict__ sumi,
                ushort_t* __restrict__ retr)
{
    int gid = blockIdx.x * 256 + threadIdx.x;   // BATCH*CHUNKS*DIM
    int d = gid & (DIM - 1);
    int c = (gid >> 10) & (CHUNKS - 1);
    int b = gid >> 16;
    size_t base   = ((size_t)(b * SEQ + c * CLEN)) * DIM + d;
    size_t bpbase = ((size_t)(c * CLEN)) * DIM + d;
    const float ms = ms_p[0];
    const float bq = bcq[d];
    float rr = sumr[gid], ri = sumi[gid];
    const float inv_sqrt_dim = 0.03125f;   // 1/sqrt(1024)
    for (int s = 0; s < CLEN; ++s) {
        size_t off = (size_t)s * DIM;
        unsigned p = ab[base + off];
        rr += bf_lo(p);
        ri += bf_hi(p);
        float qp = bp[bpbase + off] + (bf2f(qbf[base + off]) + bq) * ms;
        float sq, cq;
        sincosf(qp, &sq, &cq);
        retr[base + off] = f2bf((rr * cq + ri * sq) * inv_sqrt_dim);
    }
}

// ---------------------------------------------------------------------------
// LayerNorm per row (population variance), bf16 in -> bf16 out.
// ---------------------------------------------------------------------------
__global__ __launch_bounds__(256)
void layernorm_bf16(const ushort_t* __restrict__ in, const float* __restrict__ g,
                    const float* __restrict__ beta, ushort_t* __restrict__ out)
{
    int row = blockIdx.x;
    int t = threadIdx.x;
    ushort4 u = ((const ushort4*)(in + (size_t)row * DIM))[t];
    float vx = bf2f(u.x), vy = bf2f(u.y), vz = bf2f(u.z), vw = bf2f(u.w);
    float s  = vx + vy + vz + vw;
    float ss = vx*vx + vy*vy + vz*vz + vw*vw;
    #pragma unroll
    for (int o = 32; o >= 1; o >>= 1) {
        s  += __shfl_down(s, o);
        ss += __shfl_down(ss, o);
    }
    __shared__ float red[8];
    int wid = t >> 6, lane = t & 63;
    if (lane == 0) { red[wid] = s; red[wid + 4] = ss; }
    __syncthreads();
    if (t == 0) {
        red[0] = red[0] + red[1] + red[2] + red[3];
        red[4] = red[4] + red[5] + red[6] + red[7];
    }
    __syncthreads();
    float mu  = red[0] * (1.0f / DIM);
    float var = red[4] * (1.0f / DIM) - mu * mu;
    float rstd = rsqrtf(var + LN_EPS);
    float4 gv = ((const float4*)g)[t];
    float4 bv = ((const float4*)beta)[t];
    ushort4 o;
    o.x = f2bf((vx - mu) * rstd * gv.x + bv.x);
    o.y = f2bf((vy - mu) * rstd * gv.y + bv.y);
    o.z = f2bf((vz - mu) * rstd * gv.z + bv.z);
    o.w = f2bf((vw - mu) * rstd * gv.w + bv.w);
    ((ushort4*)(out + (size_t)row * DIM))[t] = o;
}

// ---------------------------------------------------------------------------
extern "C" void kernel_launch(void* const* d_in, const int* in_sizes, int n_in,
                              void* d_out, int out_size, void* d_ws, size_t ws_size,
                              hipStream_t stream)
{
    const float* x   = (const float*)d_in[0];
    const float* bp  = (const float*)d_in[1];
    const float* Wk  = (const float*)d_in[2];
    const float* bk  = (const float*)d_in[3];
    const float* Wv  = (const float*)d_in[4];
    const float* bv  = (const float*)d_in[5];
    const float* Wq  = (const float*)d_in[6];
    const float* bq  = (const float*)d_in[7];
    const float* Wkm = (const float*)d_in[8];
    const float* bkm = (const float*)d_in[9];
    const float* Wqm = (const float*)d_in[10];
    const float* bqm = (const float*)d_in[11];
    const float* ms  = (const float*)d_in[12];
    const float* lng = (const float*)d_in[13];
    const float* lnb = (const float*)d_in[14];
    const float* Wo  = (const float*)d_in[15];
    const float* bo  = (const float*)d_in[16];
    float* out = (float*)d_out;

    const size_t NE = (size_t)ROWS * DIM;            // 8.4M
    const size_t WN = (size_t)DIM * DIM;             // 1M

    // workspace layout
    unsigned* ab     = (unsigned*)d_ws;              // 32MB packed bf16 (a,bi)
    ushort_t* vbf    = (ushort_t*)(ab + NE);         // 16MB value_bf; retr_bf aliases
    ushort_t* kbf    = vbf + NE;                     // 16MB kplin_bf; normed_bf aliases
    ushort_t* qbf    = kbf + NE;                     // 16MB qplin_bf
    ushort_t* xbf    = qbf + NE;                     // 16MB x_bf
    ushort_t* wv_b   = xbf + NE;                     // weights: 8 x 2MB
    ushort_t* wo_b   = wv_b  + WN;
    ushort_t* wkm_b  = wo_b  + WN;
    ushort_t* wqm_b  = wkm_b + WN;
    ushort_t* wkT_b  = wqm_b + WN;
    ushort_t* wqT_b  = wkT_b + WN;
    ushort_t* wck_b  = wqT_b + WN;                   // combined Wkm*Wk
    ushort_t* wcq_b  = wck_b + WN;                   // combined Wqm*Wq
    float* bck       = (float*)(wcq_b + WN);         // 4KB
    float* bcq       = bck + DIM;                    // 4KB
    float* sumr      = bcq + DIM;                    // 1MB
    float* sumi      = sumr + (size_t)BATCH * CHUNKS * DIM;
    ushort_t* retrbf = vbf;                          // alias (value dead by pass3)
    ushort_t* normbf = kbf;                          // alias (kplin dead by LN)

    // --- conversions ---
    f32_to_bf16_k<<<(int)(NE / 2048), 256, 0, stream>>>(x, xbf);
    f32_to_bf16_k<<<(int)(WN / 2048), 256, 0, stream>>>(Wv,  wv_b);
    f32_to_bf16_k<<<(int)(WN / 2048), 256, 0, stream>>>(Wo,  wo_b);
    f32_to_bf16_k<<<(int)(WN / 2048), 256, 0, stream>>>(Wkm, wkm_b);
    f32_to_bf16_k<<<(int)(WN / 2048), 256, 0, stream>>>(Wqm, wqm_b);
    dim3 tg(32, 32);
    f32_to_bf16_T_k<<<tg, 256, 0, stream>>>(Wk, wkT_b);
    f32_to_bf16_T_k<<<tg, 256, 0, stream>>>(Wq, wqT_b);

    // --- combined biases: bck = Wkm*bk + bkm ; bcq = Wqm*bq + bqm ---
    matvec_bias_k<<<DIM / 4, 256, 0, stream>>>(Wkm, bk, bkm, bck);
    matvec_bias_k<<<DIM / 4, 256, 0, stream>>>(Wqm, bq, bqm, bcq);

    // --- combined weights: wck = Wkm @ Wk  (C[e,c] = sum_d Wkm[e,d]*WkT[c,d]) ---
    dim3 gw(DIM / 128, DIM / 128);   // 8x8
    gemm_bf16_nt<5><<<gw, 256, 0, stream>>>(wkm_b, wkT_b, nullptr, nullptr, wck_b, DIM, DIM, DIM);
    gemm_bf16_nt<5><<<gw, 256, 0, stream>>>(wqm_b, wqT_b, nullptr, nullptr, wcq_b, DIM, DIM, DIM);

    dim3 gg(ROWS / 128, DIM / 128);  // 64x8

    // value_bf = bf16(x @ Wv^T + bv)
    gemm_bf16_nt<0><<<gg, 256, 0, stream>>>(xbf, wv_b, bv, nullptr, vbf, ROWS, DIM, DIM);
    // kplin_nb = bf16(x @ wck^T)
    gemm_bf16_nt<5><<<gg, 256, 0, stream>>>(xbf, wck_b, nullptr, nullptr, kbf, ROWS, DIM, DIM);
    // qplin_nb = bf16(x @ wcq^T)
    gemm_bf16_nt<5><<<gg, 256, 0, stream>>>(xbf, wcq_b, nullptr, nullptr, qbf, ROWS, DIM, DIM);

    // phase products -> packed ab
    phase_ab_k<<<(int)(NE / 1024), 256, 0, stream>>>(vbf, kbf, bp, bck, ms, ab);

    // chunked scan + retrieved
    scan_pass1<<<(BATCH * CHUNKS * DIM) / 256, 256, 0, stream>>>(ab, sumr, sumi);
    scan_pass2<<<(BATCH * DIM * 64) / 256, 256, 0, stream>>>(sumr, sumi);
    scan_pass3<<<(BATCH * CHUNKS * DIM) / 256, 256, 0, stream>>>(ab, qbf, bp, bcq, ms,
                                                                 sumr, sumi, retrbf);

    // layernorm: retrieved -> normed_bf
    layernorm_bf16<<<ROWS, 256, 0, stream>>>(retrbf, lng, lnb, normbf);

    // out = x + normed_bf @ Wo^T + bo
    gemm_bf16_nt<4><<<gg, 256, 0, stream>>>(normbf, wo_b, bo, x, out, ROWS, DIM, DIM);
}

// Round 5
// 255.036 us; speedup vs baseline: 2.0857x; 1.0051x over previous
//
#include <hip/hip_runtime.h>
#include <math.h>

#define DIM 1024
#define SEQ 2048
#define BATCH 4
#define ROWS (BATCH*SEQ)        // 8192
#define CHUNKS 64
#define CLEN (SEQ/CHUNKS)       // 32
#define N3 3072                 // fused act width: [value | kplin | qplin]
#define LN_EPS 1e-5f

typedef unsigned short ushort_t;
typedef __attribute__((ext_vector_type(8))) short bf16x8;
typedef __attribute__((ext_vector_type(4))) float f32x4;

// fp32 -> bf16 round-to-nearest-even
__device__ inline ushort_t f2bf(float f) {
    union { float f; unsigned u; } v; v.f = f;
    unsigned r = v.u + 0x7FFFu + ((v.u >> 16) & 1u);
    return (ushort_t)(r >> 16);
}
__device__ inline float bf2f(ushort_t u) { return __uint_as_float((unsigned)u << 16); }
__device__ inline float bf_lo(unsigned p) { return __uint_as_float(p << 16); }
__device__ inline float bf_hi(unsigned p) { return __uint_as_float(p & 0xFFFF0000u); }
__device__ inline float bfq(float f) { return bf2f(f2bf(f)); }   // quantize

// ---------------------------------------------------------------------------
// fp32 -> bf16, 8 elems/thread (count multiple of 2048)
// ---------------------------------------------------------------------------
__global__ __launch_bounds__(256)
void f32_to_bf16_k(const float* __restrict__ in, ushort_t* __restrict__ out)
{
    size_t i = ((size_t)blockIdx.x * 256 + threadIdx.x) * 8;
    float4 a = *(const float4*)(in + i);
    float4 b = *(const float4*)(in + i + 4);
    ushort4 lo, hi;
    lo.x = f2bf(a.x); lo.y = f2bf(a.y); lo.z = f2bf(a.z); lo.w = f2bf(a.w);
    hi.x = f2bf(b.x); hi.y = f2bf(b.y); hi.z = f2bf(b.z); hi.w = f2bf(b.w);
    *(ushort4*)(out + i) = lo;
    *(ushort4*)(out + i + 4) = hi;
}

// ---------------------------------------------------------------------------
// fp32 -> bf16 TRANSPOSED (1024x1024): out[c][d] = bf16(in[d][c])
// ---------------------------------------------------------------------------
__global__ __launch_bounds__(256)
void f32_to_bf16_T_k(const float* __restrict__ in, ushort_t* __restrict__ out)
{
    __shared__ ushort_t tile[32][33];
    const int bx = blockIdx.x, by = blockIdx.y;
    const int tx = threadIdx.x & 31, ty = threadIdx.x >> 5;   // 32x8
    #pragma unroll
    for (int j = 0; j < 4; ++j) {
        int r = by * 32 + ty + j * 8;
        tile[ty + j * 8][tx] = f2bf(in[(size_t)r * DIM + bx * 32 + tx]);
    }
    __syncthreads();
    #pragma unroll
    for (int j = 0; j < 4; ++j) {
        int r = bx * 32 + ty + j * 8;
        out[(size_t)r * DIM + by * 32 + tx] = tile[tx][ty + j * 8];
    }
}

// ---------------------------------------------------------------------------
// bc[e] = sum_d Wm[e,d] * b_in[d] + b_out[e]   (fp32, 1 wave/row)
// ---------------------------------------------------------------------------
__global__ __launch_bounds__(256)
void matvec_bias_k(const float* __restrict__ Wm, const float* __restrict__ b_in,
                   const float* __restrict__ b_out, float* __restrict__ bc)
{
    int e = blockIdx.x * 4 + (threadIdx.x >> 6);
    int l = threadIdx.x & 63;
    float s = 0.f;
    #pragma unroll
    for (int j = 0; j < DIM / 64; ++j)
        s += Wm[(size_t)e * DIM + l + j * 64] * b_in[l + j * 64];
    #pragma unroll
    for (int o = 32; o >= 1; o >>= 1) s += __shfl_down(s, o);
    if (l == 0) bc[e] = s + b_out[e];
}

// ---------------------------------------------------------------------------
// bf16 MFMA GEMM (NT): C[m,n] = sum_k A[m,k]*W[n,k]
// MODE 4: f32 out, +bias, +resid         (final output GEMM)
// MODE 5: bf16 out, no bias              (weight-combine)
// MODE 6: bf16 out, bias only col<1024   (fused [value|kplin|qplin] GEMM)
// m97 structure: 128x128 tile, BK=32, 4 waves, global_load_lds w=16.
// ---------------------------------------------------------------------------
template<int MODE>
__global__ __launch_bounds__(256)
void gemm_bf16_nt(const ushort_t* __restrict__ A, const ushort_t* __restrict__ W,
                  const float* __restrict__ bias, const float* __restrict__ resid,
                  void* __restrict__ Cout, int M, int N, int K)
{
    __shared__ ushort_t As[128 * 32];
    __shared__ ushort_t Bs[128 * 32];
    const int bm = blockIdx.x * 128;
    const int bn = blockIdx.y * 128;
    const int t = threadIdx.x;
    const int lane = t & 63;
    const int w = t >> 6;
    const int wr = w >> 1;
    const int wc = w & 1;

    f32x4 acc[4][4] = {};

    const int fr = lane & 15;
    const int kc = (lane >> 4) * 8;

    for (int k0 = 0; k0 < K; k0 += 32) {
        #pragma unroll
        for (int i = 0; i < 2; ++i) {
            int c = t + i * 256;
            int row = c >> 2;
            int col = (c & 3) * 8;
            const ushort_t* ga = A + (size_t)(bm + row) * K + k0 + col;
            __builtin_amdgcn_global_load_lds(
                (const __attribute__((address_space(1))) void*)ga,
                (__attribute__((address_space(3))) void*)(As + (size_t)c * 8),
                16, 0, 0);
            const ushort_t* gb = W + (size_t)(bn + row) * K + k0 + col;
            __builtin_amdgcn_global_load_lds(
                (const __attribute__((address_space(1))) void*)gb,
                (__attribute__((address_space(3))) void*)(Bs + (size_t)c * 8),
                16, 0, 0);
        }
        __syncthreads();

        bf16x8 af[4], bw[4];
        #pragma unroll
        for (int m2 = 0; m2 < 4; ++m2)
            af[m2] = *(const bf16x8*)(As + (wr * 64 + m2 * 16 + fr) * 32 + kc);
        #pragma unroll
        for (int n2 = 0; n2 < 4; ++n2)
            bw[n2] = *(const bf16x8*)(Bs + (wc * 64 + n2 * 16 + fr) * 32 + kc);
        #pragma unroll
        for (int m2 = 0; m2 < 4; ++m2)
            #pragma unroll
            for (int n2 = 0; n2 < 4; ++n2)
                acc[m2][n2] = __builtin_amdgcn_mfma_f32_16x16x32_bf16(
                    af[m2], bw[n2], acc[m2][n2], 0, 0, 0);
        __syncthreads();
    }

    const int fc = lane & 15;
    const int r0 = (lane >> 4) * 4;
    #pragma unroll
    for (int m2 = 0; m2 < 4; ++m2) {
        #pragma unroll
        for (int n2 = 0; n2 < 4; ++n2) {
            int col = bn + wc * 64 + n2 * 16 + fc;
            float bv;
            if (MODE == 5)      bv = 0.0f;
            else if (MODE == 6) bv = (col < 1024) ? bias[col] : 0.0f;
            else                bv = bias[col];
            #pragma unroll
            for (int r = 0; r < 4; ++r) {
                int row = bm + wr * 64 + m2 * 16 + r0 + r;
                size_t idx = (size_t)row * N + col;
                float v = acc[m2][n2][r] + bv;
                if (MODE == 4) {
                    ((float*)Cout)[idx] = v + resid[idx];
                } else {
                    ((ushort_t*)Cout)[idx] = f2bf(v);
                }
            }
        }
    }
}

// ---------------------------------------------------------------------------
// Fused phase + scan pass 1.  Block = (b, chunk); 256 thr x 4 d = 1024 d.
// Per row s: kp = bp + (kplin + bck)*ms; ab = packed bf16 {v*cos, v*sin};
// accumulate bf16-quantized chunk sums; write sums at end.
// ---------------------------------------------------------------------------
__global__ __launch_bounds__(256)
void phase_scan1_k(const ushort_t* __restrict__ act3, const float* __restrict__ bp,
                   const float* __restrict__ bck, const float* __restrict__ ms_p,
                   unsigned* __restrict__ ab,
                   float* __restrict__ sumr, float* __restrict__ sumi)
{
    const int blk = blockIdx.x;        // b*CHUNKS + c
    const int b = blk >> 6;
    const int c = blk & (CHUNKS - 1);
    const int d0 = threadIdx.x * 4;
    const float ms = ms_p[0];
    const float4 bc4 = *(const float4*)(bck + d0);
    float sr0 = 0.f, sr1 = 0.f, sr2 = 0.f, sr3 = 0.f;
    float si0 = 0.f, si1 = 0.f, si2 = 0.f, si3 = 0.f;
    const size_t row0 = (size_t)b * SEQ + (size_t)c * CLEN;

    #pragma unroll 2
    for (int s = 0; s < CLEN; ++s) {
        size_t row = row0 + s;
        ushort4 v4 = *(const ushort4*)(act3 + row * N3 + d0);
        ushort4 k4 = *(const ushort4*)(act3 + row * N3 + 1024 + d0);
        float4 bp4 = *(const float4*)(bp + ((size_t)(c * CLEN + s)) * DIM + d0);
        uint4 o;
        float vv, kp, sn, cs, ar, ai;
        vv = bf2f(v4.x); kp = bp4.x + (bf2f(k4.x) + bc4.x) * ms;
        sincosf(kp, &sn, &cs); ar = bfq(vv * cs); ai = bfq(vv * sn);
        sr0 += ar; si0 += ai;
        o.x = (unsigned)f2bf(ar) | ((unsigned)f2bf(ai) << 16);
        vv = bf2f(v4.y); kp = bp4.y + (bf2f(k4.y) + bc4.y) * ms;
        sincosf(kp, &sn, &cs); ar = bfq(vv * cs); ai = bfq(vv * sn);
        sr1 += ar; si1 += ai;
        o.y = (unsigned)f2bf(ar) | ((unsigned)f2bf(ai) << 16);
        vv = bf2f(v4.z); kp = bp4.z + (bf2f(k4.z) + bc4.z) * ms;
        sincosf(kp, &sn, &cs); ar = bfq(vv * cs); ai = bfq(vv * sn);
        sr2 += ar; si2 += ai;
        o.z = (unsigned)f2bf(ar) | ((unsigned)f2bf(ai) << 16);
        vv = bf2f(v4.w); kp = bp4.w + (bf2f(k4.w) + bc4.w) * ms;
        sincosf(kp, &sn, &cs); ar = bfq(vv * cs); ai = bfq(vv * sn);
        sr3 += ar; si3 += ai;
        o.w = (unsigned)f2bf(ar) | ((unsigned)f2bf(ai) << 16);
        *(uint4*)(ab + row * DIM + d0) = o;
    }
    int sgid = (b * CHUNKS + c) * DIM + d0;
    *(float4*)(sumr + sgid) = make_float4(sr0, sr1, sr2, sr3);
    *(float4*)(sumi + sgid) = make_float4(si0, si1, si2, si3);
}

// ---------------------------------------------------------------------------
// Scan pass 2: exclusive prefix over CHUNKS(=64) chunk-sums, 1 wave/(b,d).
// ---------------------------------------------------------------------------
__global__ __launch_bounds__(256)
void scan_pass2(float* __restrict__ sumr, float* __restrict__ sumi)
{
    int wid  = (blockIdx.x * 256 + threadIdx.x) >> 6;   // 0..4095 = (b,d)
    int lane = threadIdx.x & 63;
    int b = wid >> 10;
    int d = wid & (DIM - 1);
    int idx = (b * CHUNKS + lane) * DIM + d;
    float r  = sumr[idx], im = sumi[idx];
    float r0 = r, i0 = im;
    #pragma unroll
    for (int o = 1; o < 64; o <<= 1) {
        float tr = __shfl_up(r, o);
        float ti = __shfl_up(im, o);
        if (lane >= o) { r += tr; im += ti; }
    }
    sumr[idx] = r - r0;    // exclusive prefix
    sumi[idx] = im - i0;
}

// ---------------------------------------------------------------------------
// Fused scan pass 3 + LayerNorm.  Block = (b, chunk); 256 thr x 4 d.
// Per row: accumulate rr/ri, retrieved in registers, block LN reduce,
// write normed bf16.  Next-row loads prefetched before the LN barriers.
// ---------------------------------------------------------------------------
__global__ __launch_bounds__(256)
void scan3_ln_k(const unsigned* __restrict__ ab, const ushort_t* __restrict__ act3,
                const float* __restrict__ bp, const float* __restrict__ bcq,
                const float* __restrict__ ms_p,
                const float* __restrict__ sumr, const float* __restrict__ sumi,
                const float* __restrict__ g, const float* __restrict__ beta,
                ushort_t* __restrict__ normbf)
{
    const int blk = blockIdx.x;
    const int b = blk >> 6;
    const int c = blk & (CHUNKS - 1);
    const int t = threadIdx.x;
    const int d0 = t * 4;
    const float ms = ms_p[0];
    const float4 bq4 = *(const float4*)(bcq + d0);
    const float4 gv  = *(const float4*)(g + d0);
    const float4 btv = *(const float4*)(beta + d0);
    const float inv_sqrt_dim = 0.03125f;

    int sgid = (b * CHUNKS + c) * DIM + d0;
    float4 rrv = *(const float4*)(sumr + sgid);
    float4 riv = *(const float4*)(sumi + sgid);
    float rr0 = rrv.x, rr1 = rrv.y, rr2 = rrv.z, rr3 = rrv.w;
    float ri0 = riv.x, ri1 = riv.y, ri2 = riv.z, ri3 = riv.w;

    const size_t row0 = (size_t)b * SEQ + (size_t)c * CLEN;
    __shared__ float red[16];
    const int wv = t >> 6, lane = t & 63;

    // prefetch row 0
    uint4   abv = *(const uint4*)(ab + row0 * DIM + d0);
    ushort4 q4  = *(const ushort4*)(act3 + row0 * N3 + 2048 + d0);
    float4  bp4 = *(const float4*)(bp + (size_t)(c * CLEN) * DIM + d0);

    for (int s = 0; s < CLEN; ++s) {
        uint4 abc = abv; ushort4 qc = q4; float4 bpc = bp4;
        if (s + 1 < CLEN) {
            size_t row = row0 + s + 1;
            abv = *(const uint4*)(ab + row * DIM + d0);
            q4  = *(const ushort4*)(act3 + row * N3 + 2048 + d0);
            bp4 = *(const float4*)(bp + (size_t)(c * CLEN + s + 1) * DIM + d0);
        }
        float r0g, r1g, r2g, r3g, qp, sq, cq;
        rr0 += bf_lo(abc.x); ri0 += bf_hi(abc.x);
        qp = bpc.x + (bf2f(qc.x) + bq4.x) * ms; sincosf(qp, &sq, &cq);
        r0g = (rr0 * cq + ri0 * sq) * inv_sqrt_dim;
        rr1 += bf_lo(abc.y); ri1 += bf_hi(abc.y);
        qp = bpc.y + (bf2f(qc.y) + bq4.y) * ms; sincosf(qp, &sq, &cq);
        r1g = (rr1 * cq + ri1 * sq) * inv_sqrt_dim;
        rr2 += bf_lo(abc.z); ri2 += bf_hi(abc.z);
        qp = bpc.z + (bf2f(qc.z) + bq4.z) * ms; sincosf(qp, &sq, &cq);
        r2g = (rr2 * cq + ri2 * sq) * inv_sqrt_dim;
        rr3 += bf_lo(abc.w); ri3 += bf_hi(abc.w);
        qp = bpc.w + (bf2f(qc.w) + bq4.w) * ms; sincosf(qp, &sq, &cq);
        r3g = (rr3 * cq + ri3 * sq) * inv_sqrt_dim;

        float ssum = r0g + r1g + r2g + r3g;
        float ssq  = r0g*r0g + r1g*r1g + r2g*r2g + r3g*r3g;
        #pragma unroll
        for (int o = 32; o >= 1; o >>= 1) {
            ssum += __shfl_down(ssum, o);
            ssq  += __shfl_down(ssq, o);
        }
        float* rd = red + (s & 1) * 8;
        if (lane == 0) { rd[wv] = ssum; rd[wv + 4] = ssq; }
        __syncthreads();
        if (t == 0) {
            rd[0] = rd[0] + rd[1] + rd[2] + rd[3];
            rd[4] = rd[4] + rd[5] + rd[6] + rd[7];
        }
        __syncthreads();
        float mu  = rd[0] * (1.0f / DIM);
        float var = rd[4] * (1.0f / DIM) - mu * mu;
        float rstd = rsqrtf(var + LN_EPS);
        ushort4 o;
        o.x = f2bf((r0g - mu) * rstd * gv.x + btv.x);
        o.y = f2bf((r1g - mu) * rstd * gv.y + btv.y);
        o.z = f2bf((r2g - mu) * rstd * gv.z + btv.z);
        o.w = f2bf((r3g - mu) * rstd * gv.w + btv.w);
        *(ushort4*)(normbf + (row0 + s) * DIM + d0) = o;
    }
}

// ---------------------------------------------------------------------------
extern "C" void kernel_launch(void* const* d_in, const int* in_sizes, int n_in,
                              void* d_out, int out_size, void* d_ws, size_t ws_size,
                              hipStream_t stream)
{
    const float* x   = (const float*)d_in[0];
    const float* bp  = (const float*)d_in[1];
    const float* Wk  = (const float*)d_in[2];
    const float* bk  = (const float*)d_in[3];
    const float* Wv  = (const float*)d_in[4];
    const float* bv  = (const float*)d_in[5];
    const float* Wq  = (const float*)d_in[6];
    const float* bq  = (const float*)d_in[7];
    const float* Wkm = (const float*)d_in[8];
    const float* bkm = (const float*)d_in[9];
    const float* Wqm = (const float*)d_in[10];
    const float* bqm = (const float*)d_in[11];
    const float* ms  = (const float*)d_in[12];
    const float* lng = (const float*)d_in[13];
    const float* lnb = (const float*)d_in[14];
    const float* Wo  = (const float*)d_in[15];
    const float* bo  = (const float*)d_in[16];
    float* out = (float*)d_out;

    const size_t NE = (size_t)ROWS * DIM;            // 8.4M
    const size_t WN = (size_t)DIM * DIM;             // 1M

    // workspace layout
    unsigned* ab     = (unsigned*)d_ws;              // 33.5MB packed bf16 (a,bi)
    ushort_t* act3   = (ushort_t*)(ab + NE);         // 50.3MB [value|kplin|qplin] bf16
    ushort_t* xbf    = act3 + (size_t)ROWS * N3;     // 16.8MB
    ushort_t* normbf = xbf + NE;                     // 16.8MB
    ushort_t* W3     = normbf + NE;                  // 6.3MB (3072 x 1024)
    ushort_t* wo_b   = W3 + (size_t)N3 * DIM;        // 2.1MB
    ushort_t* wkm_b  = wo_b + WN;
    ushort_t* wqm_b  = wkm_b + WN;
    ushort_t* wkT_b  = wqm_b + WN;
    ushort_t* wqT_b  = wkT_b + WN;
    float* bck       = (float*)(wqT_b + WN);         // 4KB
    float* bcq       = bck + DIM;
    float* sumr      = bcq + DIM;                    // 1MB
    float* sumi      = sumr + (size_t)BATCH * CHUNKS * DIM;

    // --- conversions ---
    f32_to_bf16_k<<<(int)(NE / 2048), 256, 0, stream>>>(x, xbf);
    f32_to_bf16_k<<<(int)(WN / 2048), 256, 0, stream>>>(Wv,  W3);          // rows 0..1023
    f32_to_bf16_k<<<(int)(WN / 2048), 256, 0, stream>>>(Wo,  wo_b);
    f32_to_bf16_k<<<(int)(WN / 2048), 256, 0, stream>>>(Wkm, wkm_b);
    f32_to_bf16_k<<<(int)(WN / 2048), 256, 0, stream>>>(Wqm, wqm_b);
    dim3 tg(32, 32);
    f32_to_bf16_T_k<<<tg, 256, 0, stream>>>(Wk, wkT_b);
    f32_to_bf16_T_k<<<tg, 256, 0, stream>>>(Wq, wqT_b);

    // --- combined biases: bck = Wkm*bk + bkm ; bcq = Wqm*bq + bqm ---
    matvec_bias_k<<<DIM / 4, 256, 0, stream>>>(Wkm, bk, bkm, bck);
    matvec_bias_k<<<DIM / 4, 256, 0, stream>>>(Wqm, bq, bqm, bcq);

    // --- combined weights into W3 rows 1024..3071 ---
    dim3 gw(DIM / 128, DIM / 128);   // 8x8
    gemm_bf16_nt<5><<<gw, 256, 0, stream>>>(wkm_b, wkT_b, nullptr, nullptr,
                                            W3 + WN, DIM, DIM, DIM);
    gemm_bf16_nt<5><<<gw, 256, 0, stream>>>(wqm_b, wqT_b, nullptr, nullptr,
                                            W3 + 2 * WN, DIM, DIM, DIM);

    // --- fused activation GEMM: act3 = bf16(x @ W3^T (+bv on value cols)) ---
    dim3 g3(ROWS / 128, N3 / 128);   // 64 x 24 = 1536 blocks
    gemm_bf16_nt<6><<<g3, 256, 0, stream>>>(xbf, W3, bv, nullptr,
                                            act3, ROWS, N3, DIM);

    // --- fused phase + chunk sums ---
    phase_scan1_k<<<BATCH * CHUNKS, 256, 0, stream>>>(act3, bp, bck, ms,
                                                      ab, sumr, sumi);
    // --- exclusive chunk prefix ---
    scan_pass2<<<(BATCH * DIM * 64) / 256, 256, 0, stream>>>(sumr, sumi);
    // --- fused scan + retrieved + layernorm ---
    scan3_ln_k<<<BATCH * CHUNKS, 256, 0, stream>>>(ab, act3, bp, bcq, ms,
                                                   sumr, sumi, lng, lnb, normbf);

    // --- out = x + normed @ Wo^T + bo ---
    dim3 gg(ROWS / 128, DIM / 128);  // 64x8
    gemm_bf16_nt<4><<<gg, 256, 0, stream>>>(normbf, wo_b, bo, x, out, ROWS, DIM, DIM);
}

// Round 6
// 205.093 us; speedup vs baseline: 2.5937x; 1.2435x over previous
//
#include <hip/hip_runtime.h>
#include <math.h>

#define DIM 1024
#define SEQ 2048
#define BATCH 4
#define ROWS (BATCH*SEQ)        // 8192
#define CHUNKS 64
#define CLEN (SEQ/CHUNKS)       // 32
#define N3 3072                 // fused act width: [value | kplin | qplin]
#define LN_EPS 1e-5f
#define NTK 16                  // K/BK = 1024/64 K-tiles in pipelined GEMM

typedef unsigned short ushort_t;
typedef __attribute__((ext_vector_type(8))) short bf16x8;
typedef __attribute__((ext_vector_type(4))) float f32x4;

static const size_t NE = (size_t)ROWS * DIM;   // 8.4M
static const size_t WN = (size_t)DIM * DIM;    // 1M

// fp32 -> bf16 round-to-nearest-even
__device__ inline ushort_t f2bf(float f) {
    union { float f; unsigned u; } v; v.f = f;
    unsigned r = v.u + 0x7FFFu + ((v.u >> 16) & 1u);
    return (ushort_t)(r >> 16);
}
__device__ inline float bf2f(ushort_t u) { return __uint_as_float((unsigned)u << 16); }
__device__ inline float bf_lo(unsigned p) { return __uint_as_float(p << 16); }
__device__ inline float bf_hi(unsigned p) { return __uint_as_float(p & 0xFFFF0000u); }
__device__ inline float bfq(float f) { return bf2f(f2bf(f)); }

// ---------------------------------------------------------------------------
// All plain fp32->bf16 conversions in ONE kernel (ranges are 2048-aligned so
// branches are block-uniform).  Order: x | Wv | Wo | Wkm | Wqm.
// ---------------------------------------------------------------------------
__global__ __launch_bounds__(256)
void conv_all_k(const float* __restrict__ x,  const float* __restrict__ Wv,
                const float* __restrict__ Wo, const float* __restrict__ Wkm,
                const float* __restrict__ Wqm,
                ushort_t* __restrict__ xbf,   ushort_t* __restrict__ W3,
                ushort_t* __restrict__ wo_b,  ushort_t* __restrict__ wkm_b,
                ushort_t* __restrict__ wqm_b)
{
    size_t e = ((size_t)blockIdx.x * 256 + threadIdx.x) * 8;
    const float* src; ushort_t* dst; size_t off;
    if      (e < NE)          { src = x;   dst = xbf;   off = e; }
    else if (e < NE + WN)     { src = Wv;  dst = W3;    off = e - NE; }
    else if (e < NE + 2*WN)   { src = Wo;  dst = wo_b;  off = e - NE - 2*WN + WN; }
    else if (e < NE + 3*WN)   { src = Wkm; dst = wkm_b; off = e - NE - 2*WN; }
    else                      { src = Wqm; dst = wqm_b; off = e - NE - 3*WN; }
    float4 a = *(const float4*)(src + off);
    float4 b = *(const float4*)(src + off + 4);
    ushort4 lo, hi;
    lo.x = f2bf(a.x); lo.y = f2bf(a.y); lo.z = f2bf(a.z); lo.w = f2bf(a.w);
    hi.x = f2bf(b.x); hi.y = f2bf(b.y); hi.z = f2bf(b.z); hi.w = f2bf(b.w);
    *(ushort4*)(dst + off) = lo;
    *(ushort4*)(dst + off + 4) = hi;
}

// ---------------------------------------------------------------------------
// Both weight transposes (Wk, Wq) in one kernel; z selects.
// ---------------------------------------------------------------------------
__global__ __launch_bounds__(256)
void transpose2_k(const float* __restrict__ Wk, const float* __restrict__ Wq,
                  ushort_t* __restrict__ wkT, ushort_t* __restrict__ wqT)
{
    const float* in = blockIdx.z ? Wq : Wk;
    ushort_t* out   = blockIdx.z ? wqT : wkT;
    __shared__ ushort_t tile[32][33];
    const int bx = blockIdx.x, by = blockIdx.y;
    const int tx = threadIdx.x & 31, ty = threadIdx.x >> 5;   // 32x8
    #pragma unroll
    for (int j = 0; j < 4; ++j) {
        int r = by * 32 + ty + j * 8;
        tile[ty + j * 8][tx] = f2bf(in[(size_t)r * DIM + bx * 32 + tx]);
    }
    __syncthreads();
    #pragma unroll
    for (int j = 0; j < 4; ++j) {
        int r = bx * 32 + ty + j * 8;
        out[(size_t)r * DIM + by * 32 + tx] = tile[tx][ty + j * 8];
    }
}

// ---------------------------------------------------------------------------
// Both combined-bias matvecs in one kernel; blockIdx.y selects.
//   bc = Wm @ b_in + b_out
// ---------------------------------------------------------------------------
__global__ __launch_bounds__(256)
void matvec2_k(const float* __restrict__ Wkm, const float* __restrict__ bk,
               const float* __restrict__ bkm, float* __restrict__ bck,
               const float* __restrict__ Wqm, const float* __restrict__ bq,
               const float* __restrict__ bqm, float* __restrict__ bcq)
{
    int z = blockIdx.y;
    const float* Wm  = z ? Wqm : Wkm;
    const float* bi  = z ? bq  : bk;
    const float* bo_ = z ? bqm : bkm;
    float* bc        = z ? bcq : bck;
    int e = blockIdx.x * 4 + (threadIdx.x >> 6);
    int l = threadIdx.x & 63;
    float s = 0.f;
    #pragma unroll
    for (int j = 0; j < DIM / 64; ++j)
        s += Wm[(size_t)e * DIM + l + j * 64] * bi[l + j * 64];
    #pragma unroll
    for (int o = 32; o >= 1; o >>= 1) s += __shfl_down(s, o);
    if (l == 0) bc[e] = s + bo_[e];
}

// ---------------------------------------------------------------------------
// Dual weight-combine GEMM (m97 structure), z selects (Wkm@Wk | Wqm@Wq).
// C[e,c] = sum_d A[e,d] * WT[c,d], bf16 out, 1024^3, grid (8,8,2).
// ---------------------------------------------------------------------------
__global__ __launch_bounds__(256)
void gemm_combine2(const ushort_t* __restrict__ A0, const ushort_t* __restrict__ W0,
                   ushort_t* __restrict__ C0,
                   const ushort_t* __restrict__ A1, const ushort_t* __restrict__ W1,
                   ushort_t* __restrict__ C1)
{
    const ushort_t* A = blockIdx.z ? A1 : A0;
    const ushort_t* W = blockIdx.z ? W1 : W0;
    ushort_t*       C = blockIdx.z ? C1 : C0;
    __shared__ ushort_t As[128 * 32];
    __shared__ ushort_t Bs[128 * 32];
    const int bm = blockIdx.x * 128;
    const int bn = blockIdx.y * 128;
    const int t = threadIdx.x;
    const int lane = t & 63;
    const int w = t >> 6, wr = w >> 1, wc = w & 1;
    f32x4 acc[4][4] = {};
    const int fr = lane & 15;
    const int kc = (lane >> 4) * 8;
    for (int k0 = 0; k0 < DIM; k0 += 32) {
        #pragma unroll
        for (int i = 0; i < 2; ++i) {
            int c = t + i * 256;
            int row = c >> 2;
            int col = (c & 3) * 8;
            const ushort_t* ga = A + (size_t)(bm + row) * DIM + k0 + col;
            __builtin_amdgcn_global_load_lds(
                (const __attribute__((address_space(1))) void*)ga,
                (__attribute__((address_space(3))) void*)(As + (size_t)c * 8), 16, 0, 0);
            const ushort_t* gb = W + (size_t)(bn + row) * DIM + k0 + col;
            __builtin_amdgcn_global_load_lds(
                (const __attribute__((address_space(1))) void*)gb,
                (__attribute__((address_space(3))) void*)(Bs + (size_t)c * 8), 16, 0, 0);
        }
        __syncthreads();
        bf16x8 af[4], bw[4];
        #pragma unroll
        for (int m2 = 0; m2 < 4; ++m2)
            af[m2] = *(const bf16x8*)(As + (wr * 64 + m2 * 16 + fr) * 32 + kc);
        #pragma unroll
        for (int n2 = 0; n2 < 4; ++n2)
            bw[n2] = *(const bf16x8*)(Bs + (wc * 64 + n2 * 16 + fr) * 32 + kc);
        #pragma unroll
        for (int m2 = 0; m2 < 4; ++m2)
            #pragma unroll
            for (int n2 = 0; n2 < 4; ++n2)
                acc[m2][n2] = __builtin_amdgcn_mfma_f32_16x16x32_bf16(
                    af[m2], bw[n2], acc[m2][n2], 0, 0, 0);
        __syncthreads();
    }
    const int fc = lane & 15;
    const int r0 = (lane >> 4) * 4;
    #pragma unroll
    for (int m2 = 0; m2 < 4; ++m2)
        #pragma unroll
        for (int n2 = 0; n2 < 4; ++n2) {
            int col = bn + wc * 64 + n2 * 16 + fc;
            #pragma unroll
            for (int r = 0; r < 4; ++r) {
                int row = bm + wr * 64 + m2 * 16 + r0 + r;
                C[(size_t)row * DIM + col] = f2bf(acc[m2][n2][r]);
            }
        }
}

// ---------------------------------------------------------------------------
// Deep-pipelined bf16 MFMA GEMM (NT), K=1024 fixed.
// Tile 256x128, BK=64, 512 thr (8 waves, 4Mx2N), per-wave 64x64 (4x4 frags).
// 3 LDS buffers (144KB), depth-2 prefetch, counted vmcnt(12/6/0), raw
// barriers, T2 swizzle (16B slot ^= row&7) via pre-swizzled global source
// (linear gload_lds dest) + swizzled ds_read.  T5 setprio around MFMA.
// MODE 6: bf16 out, +bias for col<1024 (act3).  MODE 4: f32 out,+bias,+resid.
// ---------------------------------------------------------------------------
template<int MODE>
__global__ __launch_bounds__(512)
void gemm_pipe(const ushort_t* __restrict__ A, const ushort_t* __restrict__ W,
               const float* __restrict__ bias, const float* __restrict__ resid,
               void* __restrict__ Cout, int N)
{
    // per buffer: A 256x64 (16384 ushort) + B 128x64 (8192 ushort) = 48KB
    __shared__ __align__(16) ushort_t lds[3 * 24576];
    const int bm = blockIdx.x * 256;
    const int bn = blockIdx.y * 128;
    const int t = threadIdx.x;          // 0..511
    const int lane = t & 63;
    const int w = t >> 6;               // 0..7
    const int wr = w >> 1;              // 0..3 (M)
    const int wc = w & 1;               // 0..1 (N)
    const int fr = lane & 15;
    const int hi = lane >> 4;           // 0..3

    f32x4 acc[4][4] = {};

    auto STAGE = [&](int kt, int b) {
        ushort_t* As = lds + b * 24576;
        ushort_t* Bs = As + 16384;
        #pragma unroll
        for (int i = 0; i < 4; ++i) {               // A: 2048 16B chunks
            int c = t + i * 512;
            int row = c >> 3, lslot = c & 7;
            int gslot = lslot ^ (row & 7);          // inverse swizzle on SOURCE
            const ushort_t* ga = A + (size_t)(bm + row) * 1024 + kt * 64 + gslot * 8;
            __builtin_amdgcn_global_load_lds(
                (const __attribute__((address_space(1))) void*)ga,
                (__attribute__((address_space(3))) void*)(As + (size_t)c * 8), 16, 0, 0);
        }
        #pragma unroll
        for (int i = 0; i < 2; ++i) {               // B: 1024 16B chunks
            int c = t + i * 512;
            int row = c >> 3, lslot = c & 7;
            int gslot = lslot ^ (row & 7);
            const ushort_t* gb = W + (size_t)(bn + row) * 1024 + kt * 64 + gslot * 8;
            __builtin_amdgcn_global_load_lds(
                (const __attribute__((address_space(1))) void*)gb,
                (__attribute__((address_space(3))) void*)(Bs + (size_t)c * 8), 16, 0, 0);
        }
    };

    auto COMPUTE = [&](int b) {
        const ushort_t* As = lds + b * 24576;
        const ushort_t* Bs = As + 16384;
        __builtin_amdgcn_s_setprio(1);
        #pragma unroll
        for (int kk = 0; kk < 2; ++kk) {
            const int gslot = kk * 4 + hi;
            bf16x8 af[4], bw[4];
            #pragma unroll
            for (int m2 = 0; m2 < 4; ++m2) {
                int row = wr * 64 + m2 * 16 + fr;
                af[m2] = *(const bf16x8*)(As + row * 64 + (gslot ^ (row & 7)) * 8);
            }
            #pragma unroll
            for (int n2 = 0; n2 < 4; ++n2) {
                int row = wc * 64 + n2 * 16 + fr;
                bw[n2] = *(const bf16x8*)(Bs + row * 64 + (gslot ^ (row & 7)) * 8);
            }
            #pragma unroll
            for (int m2 = 0; m2 < 4; ++m2)
                #pragma unroll
                for (int n2 = 0; n2 < 4; ++n2)
                    acc[m2][n2] = __builtin_amdgcn_mfma_f32_16x16x32_bf16(
                        af[m2], bw[n2], acc[m2][n2], 0, 0, 0);
        }
        __builtin_amdgcn_s_setprio(0);
    };

    // prologue: fill the 3-deep pipeline (18 loads/thread in flight)
    STAGE(0, 0); STAGE(1, 1); STAGE(2, 2);

    for (int tt = 0; tt < NTK - 2; ++tt) {
        // drain only tile tt's 6 loads (12 = 2 tiles x 6 stay in flight)
        asm volatile("s_waitcnt vmcnt(12)\n\ts_barrier" ::: "memory");
        COMPUTE(tt % 3);
        asm volatile("s_waitcnt lgkmcnt(0)\n\ts_barrier" ::: "memory");
        if (tt + 3 < NTK) STAGE(tt + 3, tt % 3);
    }
    asm volatile("s_waitcnt vmcnt(6)\n\ts_barrier" ::: "memory");
    COMPUTE((NTK - 2) % 3);
    asm volatile("s_waitcnt lgkmcnt(0)\n\ts_barrier" ::: "memory");
    asm volatile("s_waitcnt vmcnt(0)\n\ts_barrier" ::: "memory");
    COMPUTE((NTK - 1) % 3);

    // epilogue
    const int fc = fr;
    const int r0 = hi * 4;
    #pragma unroll
    for (int m2 = 0; m2 < 4; ++m2)
        #pragma unroll
        for (int n2 = 0; n2 < 4; ++n2) {
            int col = bn + wc * 64 + n2 * 16 + fc;
            float bv;
            if (MODE == 6) bv = (col < 1024) ? bias[col] : 0.0f;
            else           bv = bias[col];
            #pragma unroll
            for (int r = 0; r < 4; ++r) {
                int row = bm + wr * 64 + m2 * 16 + r0 + r;
                size_t idx = (size_t)row * N + col;
                float v = acc[m2][n2][r] + bv;
                if (MODE == 4) ((float*)Cout)[idx] = v + resid[idx];
                else           ((ushort_t*)Cout)[idx] = f2bf(v);
            }
        }
}

// ---------------------------------------------------------------------------
// Fused phase + scan pass 1.  Block = (b, chunk); 256 thr x 4 d = 1024 d.
// ---------------------------------------------------------------------------
__global__ __launch_bounds__(256)
void phase_scan1_k(const ushort_t* __restrict__ act3, const float* __restrict__ bp,
                   const float* __restrict__ bck, const float* __restrict__ ms_p,
                   unsigned* __restrict__ ab,
                   float* __restrict__ sumr, float* __restrict__ sumi)
{
    const int blk = blockIdx.x;        // b*CHUNKS + c
    const int b = blk >> 6;
    const int c = blk & (CHUNKS - 1);
    const int d0 = threadIdx.x * 4;
    const float ms = ms_p[0];
    const float4 bc4 = *(const float4*)(bck + d0);
    float sr0 = 0.f, sr1 = 0.f, sr2 = 0.f, sr3 = 0.f;
    float si0 = 0.f, si1 = 0.f, si2 = 0.f, si3 = 0.f;
    const size_t row0 = (size_t)b * SEQ + (size_t)c * CLEN;

    #pragma unroll 2
    for (int s = 0; s < CLEN; ++s) {
        size_t row = row0 + s;
        ushort4 v4 = *(const ushort4*)(act3 + row * N3 + d0);
        ushort4 k4 = *(const ushort4*)(act3 + row * N3 + 1024 + d0);
        float4 bp4 = *(const float4*)(bp + ((size_t)(c * CLEN + s)) * DIM + d0);
        uint4 o;
        float vv, kp, sn, cs, ar, ai;
        vv = bf2f(v4.x); kp = bp4.x + (bf2f(k4.x) + bc4.x) * ms;
        sincosf(kp, &sn, &cs); ar = bfq(vv * cs); ai = bfq(vv * sn);
        sr0 += ar; si0 += ai;
        o.x = (unsigned)f2bf(ar) | ((unsigned)f2bf(ai) << 16);
        vv = bf2f(v4.y); kp = bp4.y + (bf2f(k4.y) + bc4.y) * ms;
        sincosf(kp, &sn, &cs); ar = bfq(vv * cs); ai = bfq(vv * sn);
        sr1 += ar; si1 += ai;
        o.y = (unsigned)f2bf(ar) | ((unsigned)f2bf(ai) << 16);
        vv = bf2f(v4.z); kp = bp4.z + (bf2f(k4.z) + bc4.z) * ms;
        sincosf(kp, &sn, &cs); ar = bfq(vv * cs); ai = bfq(vv * sn);
        sr2 += ar; si2 += ai;
        o.z = (unsigned)f2bf(ar) | ((unsigned)f2bf(ai) << 16);
        vv = bf2f(v4.w); kp = bp4.w + (bf2f(k4.w) + bc4.w) * ms;
        sincosf(kp, &sn, &cs); ar = bfq(vv * cs); ai = bfq(vv * sn);
        sr3 += ar; si3 += ai;
        o.w = (unsigned)f2bf(ar) | ((unsigned)f2bf(ai) << 16);
        *(uint4*)(ab + row * DIM + d0) = o;
    }
    int sgid = (b * CHUNKS + c) * DIM + d0;
    *(float4*)(sumr + sgid) = make_float4(sr0, sr1, sr2, sr3);
    *(float4*)(sumi + sgid) = make_float4(si0, si1, si2, si3);
}

// ---------------------------------------------------------------------------
// Scan pass 2: exclusive prefix over CHUNKS(=64) chunk-sums, 1 wave/(b,d).
// ---------------------------------------------------------------------------
__global__ __launch_bounds__(256)
void scan_pass2(float* __restrict__ sumr, float* __restrict__ sumi)
{
    int wid  = (blockIdx.x * 256 + threadIdx.x) >> 6;   // 0..4095 = (b,d)
    int lane = threadIdx.x & 63;
    int b = wid >> 10;
    int d = wid & (DIM - 1);
    int idx = (b * CHUNKS + lane) * DIM + d;
    float r  = sumr[idx], im = sumi[idx];
    float r0 = r, i0 = im;
    #pragma unroll
    for (int o = 1; o < 64; o <<= 1) {
        float tr = __shfl_up(r, o);
        float ti = __shfl_up(im, o);
        if (lane >= o) { r += tr; im += ti; }
    }
    sumr[idx] = r - r0;    // exclusive prefix
    sumi[idx] = im - i0;
}

// ---------------------------------------------------------------------------
// Fused scan pass 3 + LayerNorm.  Block = (b, chunk); 256 thr x 4 d.
// ---------------------------------------------------------------------------
__global__ __launch_bounds__(256)
void scan3_ln_k(const unsigned* __restrict__ ab, const ushort_t* __restrict__ act3,
                const float* __restrict__ bp, const float* __restrict__ bcq,
                const float* __restrict__ ms_p,
                const float* __restrict__ sumr, const float* __restrict__ sumi,
                const float* __restrict__ g, const float* __restrict__ beta,
                ushort_t* __restrict__ normbf)
{
    const int blk = blockIdx.x;
    const int b = blk >> 6;
    const int c = blk & (CHUNKS - 1);
    const int t = threadIdx.x;
    const int d0 = t * 4;
    const float ms = ms_p[0];
    const float4 bq4 = *(const float4*)(bcq + d0);
    const float4 gv  = *(const float4*)(g + d0);
    const float4 btv = *(const float4*)(beta + d0);
    const float inv_sqrt_dim = 0.03125f;

    int sgid = (b * CHUNKS + c) * DIM + d0;
    float4 rrv = *(const float4*)(sumr + sgid);
    float4 riv = *(const float4*)(sumi + sgid);
    float rr0 = rrv.x, rr1 = rrv.y, rr2 = rrv.z, rr3 = rrv.w;
    float ri0 = riv.x, ri1 = riv.y, ri2 = riv.z, ri3 = riv.w;

    const size_t row0 = (size_t)b * SEQ + (size_t)c * CLEN;
    __shared__ float red[16];
    const int wv = t >> 6, lane = t & 63;

    uint4   abv = *(const uint4*)(ab + row0 * DIM + d0);
    ushort4 q4  = *(const ushort4*)(act3 + row0 * N3 + 2048 + d0);
    float4  bp4 = *(const float4*)(bp + (size_t)(c * CLEN) * DIM + d0);

    for (int s = 0; s < CLEN; ++s) {
        uint4 abc = abv; ushort4 qc = q4; float4 bpc = bp4;
        if (s + 1 < CLEN) {
            size_t row = row0 + s + 1;
            abv = *(const uint4*)(ab + row * DIM + d0);
            q4  = *(const ushort4*)(act3 + row * N3 + 2048 + d0);
            bp4 = *(const float4*)(bp + (size_t)(c * CLEN + s + 1) * DIM + d0);
        }
        float r0g, r1g, r2g, r3g, qp, sq, cq;
        rr0 += bf_lo(abc.x); ri0 += bf_hi(abc.x);
        qp = bpc.x + (bf2f(qc.x) + bq4.x) * ms; sincosf(qp, &sq, &cq);
        r0g = (rr0 * cq + ri0 * sq) * inv_sqrt_dim;
        rr1 += bf_lo(abc.y); ri1 += bf_hi(abc.y);
        qp = bpc.y + (bf2f(qc.y) + bq4.y) * ms; sincosf(qp, &sq, &cq);
        r1g = (rr1 * cq + ri1 * sq) * inv_sqrt_dim;
        rr2 += bf_lo(abc.z); ri2 += bf_hi(abc.z);
        qp = bpc.z + (bf2f(qc.z) + bq4.z) * ms; sincosf(qp, &sq, &cq);
        r2g = (rr2 * cq + ri2 * sq) * inv_sqrt_dim;
        rr3 += bf_lo(abc.w); ri3 += bf_hi(abc.w);
        qp = bpc.w + (bf2f(qc.w) + bq4.w) * ms; sincosf(qp, &sq, &cq);
        r3g = (rr3 * cq + ri3 * sq) * inv_sqrt_dim;

        float ssum = r0g + r1g + r2g + r3g;
        float ssq  = r0g*r0g + r1g*r1g + r2g*r2g + r3g*r3g;
        #pragma unroll
        for (int o = 32; o >= 1; o >>= 1) {
            ssum += __shfl_down(ssum, o);
            ssq  += __shfl_down(ssq, o);
        }
        float* rd = red + (s & 1) * 8;
        if (lane == 0) { rd[wv] = ssum; rd[wv + 4] = ssq; }
        __syncthreads();
        if (t == 0) {
            rd[0] = rd[0] + rd[1] + rd[2] + rd[3];
            rd[4] = rd[4] + rd[5] + rd[6] + rd[7];
        }
        __syncthreads();
        float mu  = rd[0] * (1.0f / DIM);
        float var = rd[4] * (1.0f / DIM) - mu * mu;
        float rstd = rsqrtf(var + LN_EPS);
        ushort4 o;
        o.x = f2bf((r0g - mu) * rstd * gv.x + btv.x);
        o.y = f2bf((r1g - mu) * rstd * gv.y + btv.y);
        o.z = f2bf((r2g - mu) * rstd * gv.z + btv.z);
        o.w = f2bf((r3g - mu) * rstd * gv.w + btv.w);
        *(ushort4*)(normbf + (row0 + s) * DIM + d0) = o;
    }
}

// ---------------------------------------------------------------------------
extern "C" void kernel_launch(void* const* d_in, const int* in_sizes, int n_in,
                              void* d_out, int out_size, void* d_ws, size_t ws_size,
                              hipStream_t stream)
{
    const float* x   = (const float*)d_in[0];
    const float* bp  = (const float*)d_in[1];
    const float* Wk  = (const float*)d_in[2];
    const float* bk  = (const float*)d_in[3];
    const float* Wv  = (const float*)d_in[4];
    const float* bv  = (const float*)d_in[5];
    const float* Wq  = (const float*)d_in[6];
    const float* bq  = (const float*)d_in[7];
    const float* Wkm = (const float*)d_in[8];
    const float* bkm = (const float*)d_in[9];
    const float* Wqm = (const float*)d_in[10];
    const float* bqm = (const float*)d_in[11];
    const float* ms  = (const float*)d_in[12];
    const float* lng = (const float*)d_in[13];
    const float* lnb = (const float*)d_in[14];
    const float* Wo  = (const float*)d_in[15];
    const float* bo  = (const float*)d_in[16];
    float* out = (float*)d_out;

    // workspace layout
    unsigned* ab     = (unsigned*)d_ws;              // 33.5MB packed bf16 (a,bi)
    ushort_t* act3   = (ushort_t*)(ab + NE);         // 50.3MB [value|kplin|qplin]
    ushort_t* xbf    = act3 + (size_t)ROWS * N3;     // 16.8MB
    ushort_t* normbf = xbf + NE;                     // 16.8MB
    ushort_t* W3     = normbf + NE;                  // 6.3MB (3072 x 1024)
    ushort_t* wo_b   = W3 + (size_t)N3 * DIM;        // 2.1MB
    ushort_t* wkm_b  = wo_b + WN;
    ushort_t* wqm_b  = wkm_b + WN;
    ushort_t* wkT_b  = wqm_b + WN;
    ushort_t* wqT_b  = wkT_b + WN;
    float* bck       = (float*)(wqT_b + WN);         // 4KB
    float* bcq       = bck + DIM;
    float* sumr      = bcq + DIM;                    // 1MB
    float* sumi      = sumr + (size_t)BATCH * CHUNKS * DIM;

    // --- all plain conversions in one dispatch ---
    conv_all_k<<<(int)((NE + 4 * WN) / 2048), 256, 0, stream>>>(
        x, Wv, Wo, Wkm, Wqm, xbf, W3, wo_b, wkm_b, wqm_b);
    // --- both transposes ---
    dim3 tg(32, 32, 2);
    transpose2_k<<<tg, 256, 0, stream>>>(Wk, Wq, wkT_b, wqT_b);
    // --- both combined biases ---
    dim3 mg(DIM / 4, 2);
    matvec2_k<<<mg, 256, 0, stream>>>(Wkm, bk, bkm, bck, Wqm, bq, bqm, bcq);
    // --- both weight combines: W3 rows 1024..2047 and 2048..3071 ---
    dim3 gw(DIM / 128, DIM / 128, 2);
    gemm_combine2<<<gw, 256, 0, stream>>>(wkm_b, wkT_b, W3 + WN,
                                          wqm_b, wqT_b, W3 + 2 * WN);

    // --- fused activation GEMM (pipelined): act3 = bf16(x @ W3^T (+bv)) ---
    dim3 g3(ROWS / 256, N3 / 128);   // 32 x 24 = 768 blocks
    gemm_pipe<6><<<g3, 512, 0, stream>>>(xbf, W3, bv, nullptr, act3, N3);

    // --- fused phase + chunk sums ---
    phase_scan1_k<<<BATCH * CHUNKS, 256, 0, stream>>>(act3, bp, bck, ms,
                                                      ab, sumr, sumi);
    // --- exclusive chunk prefix ---
    scan_pass2<<<(BATCH * DIM * 64) / 256, 256, 0, stream>>>(sumr, sumi);
    // --- fused scan + retrieved + layernorm ---
    scan3_ln_k<<<BATCH * CHUNKS, 256, 0, stream>>>(ab, act3, bp, bcq, ms,
                                                   sumr, sumi, lng, lnb, normbf);

    // --- out = x + normed @ Wo^T + bo (pipelined) ---
    dim3 gg(ROWS / 256, DIM / 128);  // 32 x 8 = 256 blocks
    gemm_pipe<4><<<gg, 512, 0, stream>>>(normbf, wo_b, bo, x, out, DIM);
}

// Round 7
// 187.579 us; speedup vs baseline: 2.8358x; 1.0934x over previous
//
#include <hip/hip_runtime.h>
#include <math.h>

#define DIM 1024
#define SEQ 2048
#define BATCH 4
#define ROWS (BATCH*SEQ)        // 8192
#define CHUNKS 128
#define CLEN (SEQ/CHUNKS)       // 16
#define N3 3072                 // fused act width: [value | kplin | qplin]
#define LN_EPS 1e-5f
#define NTK 16                  // K/BK = 1024/64 K-tiles in pipelined GEMM

typedef unsigned short ushort_t;
typedef __attribute__((ext_vector_type(8))) short bf16x8;
typedef __attribute__((ext_vector_type(4))) float f32x4;

static const size_t NE = (size_t)ROWS * DIM;   // 8.4M
static const size_t WN = (size_t)DIM * DIM;    // 1M

// fp32 -> bf16 round-to-nearest-even
__device__ inline ushort_t f2bf(float f) {
    union { float f; unsigned u; } v; v.f = f;
    unsigned r = v.u + 0x7FFFu + ((v.u >> 16) & 1u);
    return (ushort_t)(r >> 16);
}
__device__ inline float bf2f(ushort_t u) { return __uint_as_float((unsigned)u << 16); }
__device__ inline float bf_lo(unsigned p) { return __uint_as_float(p << 16); }
__device__ inline float bf_hi(unsigned p) { return __uint_as_float(p & 0xFFFF0000u); }
__device__ inline float bfq(float f) { return bf2f(f2bf(f)); }

// ---------------------------------------------------------------------------
// All plain fp32->bf16 conversions in ONE kernel.  Order: x | Wv | Wo | Wkm | Wqm.
// ---------------------------------------------------------------------------
__global__ __launch_bounds__(256)
void conv_all_k(const float* __restrict__ x,  const float* __restrict__ Wv,
                const float* __restrict__ Wo, const float* __restrict__ Wkm,
                const float* __restrict__ Wqm,
                ushort_t* __restrict__ xbf,   ushort_t* __restrict__ W3,
                ushort_t* __restrict__ wo_b,  ushort_t* __restrict__ wkm_b,
                ushort_t* __restrict__ wqm_b)
{
    size_t e = ((size_t)blockIdx.x * 256 + threadIdx.x) * 8;
    const float* src; ushort_t* dst; size_t off;
    if      (e < NE)          { src = x;   dst = xbf;   off = e; }
    else if (e < NE + WN)     { src = Wv;  dst = W3;    off = e - NE; }
    else if (e < NE + 2*WN)   { src = Wo;  dst = wo_b;  off = e - NE - 2*WN + WN; }
    else if (e < NE + 3*WN)   { src = Wkm; dst = wkm_b; off = e - NE - 2*WN; }
    else                      { src = Wqm; dst = wqm_b; off = e - NE - 3*WN; }
    float4 a = *(const float4*)(src + off);
    float4 b = *(const float4*)(src + off + 4);
    ushort4 lo, hi;
    lo.x = f2bf(a.x); lo.y = f2bf(a.y); lo.z = f2bf(a.z); lo.w = f2bf(a.w);
    hi.x = f2bf(b.x); hi.y = f2bf(b.y); hi.z = f2bf(b.z); hi.w = f2bf(b.w);
    *(ushort4*)(dst + off) = lo;
    *(ushort4*)(dst + off + 4) = hi;
}

// ---------------------------------------------------------------------------
// Both weight transposes (Wk, Wq) in one kernel; z selects.
// ---------------------------------------------------------------------------
__global__ __launch_bounds__(256)
void transpose2_k(const float* __restrict__ Wk, const float* __restrict__ Wq,
                  ushort_t* __restrict__ wkT, ushort_t* __restrict__ wqT)
{
    const float* in = blockIdx.z ? Wq : Wk;
    ushort_t* out   = blockIdx.z ? wqT : wkT;
    __shared__ ushort_t tile[32][33];
    const int bx = blockIdx.x, by = blockIdx.y;
    const int tx = threadIdx.x & 31, ty = threadIdx.x >> 5;   // 32x8
    #pragma unroll
    for (int j = 0; j < 4; ++j) {
        int r = by * 32 + ty + j * 8;
        tile[ty + j * 8][tx] = f2bf(in[(size_t)r * DIM + bx * 32 + tx]);
    }
    __syncthreads();
    #pragma unroll
    for (int j = 0; j < 4; ++j) {
        int r = bx * 32 + ty + j * 8;
        out[(size_t)r * DIM + by * 32 + tx] = tile[tx][ty + j * 8];
    }
}

// ---------------------------------------------------------------------------
// Both combined-bias matvecs in one kernel; blockIdx.y selects.
// ---------------------------------------------------------------------------
__global__ __launch_bounds__(256)
void matvec2_k(const float* __restrict__ Wkm, const float* __restrict__ bk,
               const float* __restrict__ bkm, float* __restrict__ bck,
               const float* __restrict__ Wqm, const float* __restrict__ bq,
               const float* __restrict__ bqm, float* __restrict__ bcq)
{
    int z = blockIdx.y;
    const float* Wm  = z ? Wqm : Wkm;
    const float* bi  = z ? bq  : bk;
    const float* bo_ = z ? bqm : bkm;
    float* bc        = z ? bcq : bck;
    int e = blockIdx.x * 4 + (threadIdx.x >> 6);
    int l = threadIdx.x & 63;
    float s = 0.f;
    #pragma unroll
    for (int j = 0; j < DIM / 64; ++j)
        s += Wm[(size_t)e * DIM + l + j * 64] * bi[l + j * 64];
    #pragma unroll
    for (int o = 32; o >= 1; o >>= 1) s += __shfl_down(s, o);
    if (l == 0) bc[e] = s + bo_[e];
}

// ---------------------------------------------------------------------------
// Dual weight-combine GEMM (m97 structure), z selects (Wkm@Wk | Wqm@Wq).
// ---------------------------------------------------------------------------
__global__ __launch_bounds__(256)
void gemm_combine2(const ushort_t* __restrict__ A0, const ushort_t* __restrict__ W0,
                   ushort_t* __restrict__ C0,
                   const ushort_t* __restrict__ A1, const ushort_t* __restrict__ W1,
                   ushort_t* __restrict__ C1)
{
    const ushort_t* A = blockIdx.z ? A1 : A0;
    const ushort_t* W = blockIdx.z ? W1 : W0;
    ushort_t*       C = blockIdx.z ? C1 : C0;
    __shared__ ushort_t As[128 * 32];
    __shared__ ushort_t Bs[128 * 32];
    const int bm = blockIdx.x * 128;
    const int bn = blockIdx.y * 128;
    const int t = threadIdx.x;
    const int lane = t & 63;
    const int w = t >> 6, wr = w >> 1, wc = w & 1;
    f32x4 acc[4][4] = {};
    const int fr = lane & 15;
    const int kc = (lane >> 4) * 8;
    for (int k0 = 0; k0 < DIM; k0 += 32) {
        #pragma unroll
        for (int i = 0; i < 2; ++i) {
            int c = t + i * 256;
            int row = c >> 2;
            int col = (c & 3) * 8;
            const ushort_t* ga = A + (size_t)(bm + row) * DIM + k0 + col;
            __builtin_amdgcn_global_load_lds(
                (const __attribute__((address_space(1))) void*)ga,
                (__attribute__((address_space(3))) void*)(As + (size_t)c * 8), 16, 0, 0);
            const ushort_t* gb = W + (size_t)(bn + row) * DIM + k0 + col;
            __builtin_amdgcn_global_load_lds(
                (const __attribute__((address_space(1))) void*)gb,
                (__attribute__((address_space(3))) void*)(Bs + (size_t)c * 8), 16, 0, 0);
        }
        __syncthreads();
        bf16x8 af[4], bw[4];
        #pragma unroll
        for (int m2 = 0; m2 < 4; ++m2)
            af[m2] = *(const bf16x8*)(As + (wr * 64 + m2 * 16 + fr) * 32 + kc);
        #pragma unroll
        for (int n2 = 0; n2 < 4; ++n2)
            bw[n2] = *(const bf16x8*)(Bs + (wc * 64 + n2 * 16 + fr) * 32 + kc);
        #pragma unroll
        for (int m2 = 0; m2 < 4; ++m2)
            #pragma unroll
            for (int n2 = 0; n2 < 4; ++n2)
                acc[m2][n2] = __builtin_amdgcn_mfma_f32_16x16x32_bf16(
                    af[m2], bw[n2], acc[m2][n2], 0, 0, 0);
        __syncthreads();
    }
    const int fc = lane & 15;
    const int r0 = (lane >> 4) * 4;
    #pragma unroll
    for (int m2 = 0; m2 < 4; ++m2)
        #pragma unroll
        for (int n2 = 0; n2 < 4; ++n2) {
            int col = bn + wc * 64 + n2 * 16 + fc;
            #pragma unroll
            for (int r = 0; r < 4; ++r) {
                int row = bm + wr * 64 + m2 * 16 + r0 + r;
                C[(size_t)row * DIM + col] = f2bf(acc[m2][n2][r]);
            }
        }
}

// ---------------------------------------------------------------------------
// Deep-pipelined phase-split bf16 MFMA GEMM (NT), K=1024 fixed.
// Tile 256x128, BK=64, 512 thr (8 waves, 4Mx2N), per-wave 64x64 (4x4 frags).
// 3 LDS buffers (144KB), depth-2 prefetch.  Per K-tile:
//   tile-top: vmcnt(6) (last tile: 0) + barrier   <- tile data visible
//   phase kk=0: 8 ds_read | stage 3 G-loads (tile tt+2) | bar | lgkm(0) |
//               sched_barrier | setprio(1) 16 MFMA setprio(0)
//   phase kk=1: same for the other K-half
// vmcnt never drains to 0 in steady state (T4); T2 swizzle; T5 setprio.
// MODE 6: bf16 out, +bias for col<1024.  MODE 4: f32 out, +bias, +resid.
// ---------------------------------------------------------------------------
template<int MODE>
__global__ __launch_bounds__(512)
void gemm_pipe(const ushort_t* __restrict__ A, const ushort_t* __restrict__ W,
               const float* __restrict__ bias, const float* __restrict__ resid,
               void* __restrict__ Cout, int N)
{
    // per buffer: A 256x64 (16384 ushort) + B 128x64 (8192 ushort) = 48KB
    __shared__ __align__(16) ushort_t lds[3 * 24576];
    const int bm = blockIdx.x * 256;
    const int bn = blockIdx.y * 128;
    const int t = threadIdx.x;          // 0..511
    const int lane = t & 63;
    const int w = t >> 6;               // 0..7
    const int wr = w >> 1;              // 0..3 (M)
    const int wc = w & 1;               // 0..1 (N)
    const int fr = lane & 15;
    const int hi = lane >> 4;           // 0..3

    f32x4 acc[4][4] = {};

    // stage half h of tile kt into buffer b: h=0 -> A chunks 0,1 + B chunk 0;
    // h=1 -> A chunks 2,3 + B chunk 1.  3 gloads/thread per half.
    auto STAGE_H = [&](int kt, int b, int h) {
        ushort_t* As = lds + b * 24576;
        ushort_t* Bs = As + 16384;
        #pragma unroll
        for (int i = 0; i < 2; ++i) {
            int c = t + (h * 2 + i) * 512;
            int row = c >> 3, lslot = c & 7;
            int gslot = lslot ^ (row & 7);          // inverse swizzle on SOURCE
            const ushort_t* ga = A + (size_t)(bm + row) * 1024 + kt * 64 + gslot * 8;
            __builtin_amdgcn_global_load_lds(
                (const __attribute__((address_space(1))) void*)ga,
                (__attribute__((address_space(3))) void*)(As + (size_t)c * 8), 16, 0, 0);
        }
        {
            int c = t + h * 512;
            int row = c >> 3, lslot = c & 7;
            int gslot = lslot ^ (row & 7);
            const ushort_t* gb = W + (size_t)(bn + row) * 1024 + kt * 64 + gslot * 8;
            __builtin_amdgcn_global_load_lds(
                (const __attribute__((address_space(1))) void*)gb,
                (__attribute__((address_space(3))) void*)(Bs + (size_t)c * 8), 16, 0, 0);
        }
    };

    // one phase: ds_read this kk-half's frags, stage half of tile tt+2,
    // barrier, lgkm(0), pinned MFMA cluster.
    auto PHASE = [&](int b, int kk, int kt_next, bool do_stage) {
        const ushort_t* As = lds + b * 24576;
        const ushort_t* Bs = As + 16384;
        const int gslot = kk * 4 + hi;
        bf16x8 af[4], bw[4];
        #pragma unroll
        for (int m2 = 0; m2 < 4; ++m2) {
            int row = wr * 64 + m2 * 16 + fr;
            af[m2] = *(const bf16x8*)(As + row * 64 + (gslot ^ (row & 7)) * 8);
        }
        #pragma unroll
        for (int n2 = 0; n2 < 4; ++n2) {
            int row = wc * 64 + n2 * 16 + fr;
            bw[n2] = *(const bf16x8*)(Bs + row * 64 + (gslot ^ (row & 7)) * 8);
        }
        if (do_stage) STAGE_H(kt_next, kt_next % 3, kk);
        __builtin_amdgcn_s_barrier();
        asm volatile("s_waitcnt lgkmcnt(0)" ::: "memory");
        __builtin_amdgcn_sched_barrier(0);
        __builtin_amdgcn_s_setprio(1);
        #pragma unroll
        for (int m2 = 0; m2 < 4; ++m2)
            #pragma unroll
            for (int n2 = 0; n2 < 4; ++n2)
                acc[m2][n2] = __builtin_amdgcn_mfma_f32_16x16x32_bf16(
                    af[m2], bw[n2], acc[m2][n2], 0, 0, 0);
        __builtin_amdgcn_s_setprio(0);
    };

    // prologue: stage tiles 0 and 1 fully (12 loads/thread in flight)
    STAGE_H(0, 0, 0); STAGE_H(0, 0, 1);
    STAGE_H(1, 1, 0); STAGE_H(1, 1, 1);

    for (int tt = 0; tt < NTK; ++tt) {
        if (tt < NTK - 1) asm volatile("s_waitcnt vmcnt(6)" ::: "memory");
        else              asm volatile("s_waitcnt vmcnt(0)" ::: "memory");
        __builtin_amdgcn_s_barrier();
        const bool st = (tt + 2 < NTK);
        PHASE(tt % 3, 0, tt + 2, st);
        PHASE(tt % 3, 1, tt + 2, st);
    }

    // epilogue
    const int fc = fr;
    const int r0 = hi * 4;
    #pragma unroll
    for (int m2 = 0; m2 < 4; ++m2)
        #pragma unroll
        for (int n2 = 0; n2 < 4; ++n2) {
            int col = bn + wc * 64 + n2 * 16 + fc;
            float bv;
            if (MODE == 6) bv = (col < 1024) ? bias[col] : 0.0f;
            else           bv = bias[col];
            #pragma unroll
            for (int r = 0; r < 4; ++r) {
                int row = bm + wr * 64 + m2 * 16 + r0 + r;
                size_t idx = (size_t)row * N + col;
                float v = acc[m2][n2][r] + bv;
                if (MODE == 4) ((float*)Cout)[idx] = v + resid[idx];
                else           ((ushort_t*)Cout)[idx] = f2bf(v);
            }
        }
}

// ---------------------------------------------------------------------------
// Fused phase + scan pass 1.  Block = (b, chunk); 256 thr x 4 d = 1024 d.
// ---------------------------------------------------------------------------
__global__ __launch_bounds__(256)
void phase_scan1_k(const ushort_t* __restrict__ act3, const float* __restrict__ bp,
                   const float* __restrict__ bck, const float* __restrict__ ms_p,
                   unsigned* __restrict__ ab,
                   float* __restrict__ sumr, float* __restrict__ sumi)
{
    const int blk = blockIdx.x;        // b*CHUNKS + c
    const int b = blk >> 7;
    const int c = blk & (CHUNKS - 1);
    const int d0 = threadIdx.x * 4;
    const float ms = ms_p[0];
    const float4 bc4 = *(const float4*)(bck + d0);
    float sr0 = 0.f, sr1 = 0.f, sr2 = 0.f, sr3 = 0.f;
    float si0 = 0.f, si1 = 0.f, si2 = 0.f, si3 = 0.f;
    const size_t row0 = (size_t)b * SEQ + (size_t)c * CLEN;

    #pragma unroll 2
    for (int s = 0; s < CLEN; ++s) {
        size_t row = row0 + s;
        ushort4 v4 = *(const ushort4*)(act3 + row * N3 + d0);
        ushort4 k4 = *(const ushort4*)(act3 + row * N3 + 1024 + d0);
        float4 bp4 = *(const float4*)(bp + ((size_t)(c * CLEN + s)) * DIM + d0);
        uint4 o;
        float vv, kp, sn, cs, ar, ai;
        vv = bf2f(v4.x); kp = bp4.x + (bf2f(k4.x) + bc4.x) * ms;
        sincosf(kp, &sn, &cs); ar = bfq(vv * cs); ai = bfq(vv * sn);
        sr0 += ar; si0 += ai;
        o.x = (unsigned)f2bf(ar) | ((unsigned)f2bf(ai) << 16);
        vv = bf2f(v4.y); kp = bp4.y + (bf2f(k4.y) + bc4.y) * ms;
        sincosf(kp, &sn, &cs); ar = bfq(vv * cs); ai = bfq(vv * sn);
        sr1 += ar; si1 += ai;
        o.y = (unsigned)f2bf(ar) | ((unsigned)f2bf(ai) << 16);
        vv = bf2f(v4.z); kp = bp4.z + (bf2f(k4.z) + bc4.z) * ms;
        sincosf(kp, &sn, &cs); ar = bfq(vv * cs); ai = bfq(vv * sn);
        sr2 += ar; si2 += ai;
        o.z = (unsigned)f2bf(ar) | ((unsigned)f2bf(ai) << 16);
        vv = bf2f(v4.w); kp = bp4.w + (bf2f(k4.w) + bc4.w) * ms;
        sincosf(kp, &sn, &cs); ar = bfq(vv * cs); ai = bfq(vv * sn);
        sr3 += ar; si3 += ai;
        o.w = (unsigned)f2bf(ar) | ((unsigned)f2bf(ai) << 16);
        *(uint4*)(ab + row * DIM + d0) = o;
    }
    int sgid = (b * CHUNKS + c) * DIM + d0;
    *(float4*)(sumr + sgid) = make_float4(sr0, sr1, sr2, sr3);
    *(float4*)(sumi + sgid) = make_float4(si0, si1, si2, si3);
}

// ---------------------------------------------------------------------------
// Scan pass 2: exclusive prefix over CHUNKS(=128) chunk-sums, 1 wave/(b,d),
// 2 chunks per lane.
// ---------------------------------------------------------------------------
__global__ __launch_bounds__(256)
void scan_pass2(float* __restrict__ sumr, float* __restrict__ sumi)
{
    int wid  = (blockIdx.x * 256 + threadIdx.x) >> 6;   // 0..4095 = (b,d)
    int lane = threadIdx.x & 63;
    int b = wid >> 10;
    int d = wid & (DIM - 1);
    int i0 = (b * CHUNKS + 2 * lane) * DIM + d;
    int i1 = i0 + DIM;
    float r0 = sumr[i0], r1 = sumr[i1];
    float s0 = sumi[i0], s1 = sumi[i1];
    float pr = r0 + r1, pi = s0 + s1;
    float er = pr, ei = pi;
    #pragma unroll
    for (int o = 1; o < 64; o <<= 1) {
        float tr = __shfl_up(er, o);
        float ti = __shfl_up(ei, o);
        if (lane >= o) { er += tr; ei += ti; }
    }
    er -= pr; ei -= pi;               // exclusive prefix over pairs
    sumr[i0] = er;       sumi[i0] = ei;
    sumr[i1] = er + r0;  sumi[i1] = ei + s0;
}

// ---------------------------------------------------------------------------
// Fused scan pass 3 + LayerNorm.  Block = (b, chunk); 256 thr x 4 d.
// ---------------------------------------------------------------------------
__global__ __launch_bounds__(256)
void scan3_ln_k(const unsigned* __restrict__ ab, const ushort_t* __restrict__ act3,
                const float* __restrict__ bp, const float* __restrict__ bcq,
                const float* __restrict__ ms_p,
                const float* __restrict__ sumr, const float* __restrict__ sumi,
                const float* __restrict__ g, const float* __restrict__ beta,
                ushort_t* __restrict__ normbf)
{
    const int blk = blockIdx.x;
    const int b = blk >> 7;
    const int c = blk & (CHUNKS - 1);
    const int t = threadIdx.x;
    const int d0 = t * 4;
    const float ms = ms_p[0];
    const float4 bq4 = *(const float4*)(bcq + d0);
    const float4 gv  = *(const float4*)(g + d0);
    const float4 btv = *(const float4*)(beta + d0);
    const float inv_sqrt_dim = 0.03125f;

    int sgid = (b * CHUNKS + c) * DIM + d0;
    float4 rrv = *(const float4*)(sumr + sgid);
    float4 riv = *(const float4*)(sumi + sgid);
    float rr0 = rrv.x, rr1 = rrv.y, rr2 = rrv.z, rr3 = rrv.w;
    float ri0 = riv.x, ri1 = riv.y, ri2 = riv.z, ri3 = riv.w;

    const size_t row0 = (size_t)b * SEQ + (size_t)c * CLEN;
    __shared__ float red[16];
    const int wv = t >> 6, lane = t & 63;

    uint4   abv = *(const uint4*)(ab + row0 * DIM + d0);
    ushort4 q4  = *(const ushort4*)(act3 + row0 * N3 + 2048 + d0);
    float4  bp4 = *(const float4*)(bp + (size_t)(c * CLEN) * DIM + d0);

    for (int s = 0; s < CLEN; ++s) {
        uint4 abc = abv; ushort4 qc = q4; float4 bpc = bp4;
        if (s + 1 < CLEN) {
            size_t row = row0 + s + 1;
            abv = *(const uint4*)(ab + row * DIM + d0);
            q4  = *(const ushort4*)(act3 + row * N3 + 2048 + d0);
            bp4 = *(const float4*)(bp + (size_t)(c * CLEN + s + 1) * DIM + d0);
        }
        float r0g, r1g, r2g, r3g, qp, sq, cq;
        rr0 += bf_lo(abc.x); ri0 += bf_hi(abc.x);
        qp = bpc.x + (bf2f(qc.x) + bq4.x) * ms; sincosf(qp, &sq, &cq);
        r0g = (rr0 * cq + ri0 * sq) * inv_sqrt_dim;
        rr1 += bf_lo(abc.y); ri1 += bf_hi(abc.y);
        qp = bpc.y + (bf2f(qc.y) + bq4.y) * ms; sincosf(qp, &sq, &cq);
        r1g = (rr1 * cq + ri1 * sq) * inv_sqrt_dim;
        rr2 += bf_lo(abc.z); ri2 += bf_hi(abc.z);
        qp = bpc.z + (bf2f(qc.z) + bq4.z) * ms; sincosf(qp, &sq, &cq);
        r2g = (rr2 * cq + ri2 * sq) * inv_sqrt_dim;
        rr3 += bf_lo(abc.w); ri3 += bf_hi(abc.w);
        qp = bpc.w + (bf2f(qc.w) + bq4.w) * ms; sincosf(qp, &sq, &cq);
        r3g = (rr3 * cq + ri3 * sq) * inv_sqrt_dim;

        float ssum = r0g + r1g + r2g + r3g;
        float ssq  = r0g*r0g + r1g*r1g + r2g*r2g + r3g*r3g;
        #pragma unroll
        for (int o = 32; o >= 1; o >>= 1) {
            ssum += __shfl_down(ssum, o);
            ssq  += __shfl_down(ssq, o);
        }
        float* rd = red + (s & 1) * 8;
        if (lane == 0) { rd[wv] = ssum; rd[wv + 4] = ssq; }
        __syncthreads();
        if (t == 0) {
            rd[0] = rd[0] + rd[1] + rd[2] + rd[3];
            rd[4] = rd[4] + rd[5] + rd[6] + rd[7];
        }
        __syncthreads();
        float mu  = rd[0] * (1.0f / DIM);
        float var = rd[4] * (1.0f / DIM) - mu * mu;
        float rstd = rsqrtf(var + LN_EPS);
        ushort4 o;
        o.x = f2bf((r0g - mu) * rstd * gv.x + btv.x);
        o.y = f2bf((r1g - mu) * rstd * gv.y + btv.y);
        o.z = f2bf((r2g - mu) * rstd * gv.z + btv.z);
        o.w = f2bf((r3g - mu) * rstd * gv.w + btv.w);
        *(ushort4*)(normbf + (row0 + s) * DIM + d0) = o;
    }
}

// ---------------------------------------------------------------------------
extern "C" void kernel_launch(void* const* d_in, const int* in_sizes, int n_in,
                              void* d_out, int out_size, void* d_ws, size_t ws_size,
                              hipStream_t stream)
{
    const float* x   = (const float*)d_in[0];
    const float* bp  = (const float*)d_in[1];
    const float* Wk  = (const float*)d_in[2];
    const float* bk  = (const float*)d_in[3];
    const float* Wv  = (const float*)d_in[4];
    const float* bv  = (const float*)d_in[5];
    const float* Wq  = (const float*)d_in[6];
    const float* bq  = (const float*)d_in[7];
    const float* Wkm = (const float*)d_in[8];
    const float* bkm = (const float*)d_in[9];
    const float* Wqm = (const float*)d_in[10];
    const float* bqm = (const float*)d_in[11];
    const float* ms  = (const float*)d_in[12];
    const float* lng = (const float*)d_in[13];
    const float* lnb = (const float*)d_in[14];
    const float* Wo  = (const float*)d_in[15];
    const float* bo  = (const float*)d_in[16];
    float* out = (float*)d_out;

    // workspace layout
    unsigned* ab     = (unsigned*)d_ws;              // 33.5MB packed bf16 (a,bi)
    ushort_t* act3   = (ushort_t*)(ab + NE);         // 50.3MB [value|kplin|qplin]
    ushort_t* xbf    = act3 + (size_t)ROWS * N3;     // 16.8MB
    ushort_t* normbf = xbf + NE;                     // 16.8MB
    ushort_t* W3     = normbf + NE;                  // 6.3MB (3072 x 1024)
    ushort_t* wo_b   = W3 + (size_t)N3 * DIM;        // 2.1MB
    ushort_t* wkm_b  = wo_b + WN;
    ushort_t* wqm_b  = wkm_b + WN;
    ushort_t* wkT_b  = wqm_b + WN;
    ushort_t* wqT_b  = wkT_b + WN;
    float* bck       = (float*)(wqT_b + WN);         // 4KB
    float* bcq       = bck + DIM;
    float* sumr      = bcq + DIM;                    // 2MB each
    float* sumi      = sumr + (size_t)BATCH * CHUNKS * DIM;

    // --- all plain conversions in one dispatch ---
    conv_all_k<<<(int)((NE + 4 * WN) / 2048), 256, 0, stream>>>(
        x, Wv, Wo, Wkm, Wqm, xbf, W3, wo_b, wkm_b, wqm_b);
    // --- both transposes ---
    dim3 tg(32, 32, 2);
    transpose2_k<<<tg, 256, 0, stream>>>(Wk, Wq, wkT_b, wqT_b);
    // --- both combined biases ---
    dim3 mg(DIM / 4, 2);
    matvec2_k<<<mg, 256, 0, stream>>>(Wkm, bk, bkm, bck, Wqm, bq, bqm, bcq);
    // --- both weight combines: W3 rows 1024..2047 and 2048..3071 ---
    dim3 gw(DIM / 128, DIM / 128, 2);
    gemm_combine2<<<gw, 256, 0, stream>>>(wkm_b, wkT_b, W3 + WN,
                                          wqm_b, wqT_b, W3 + 2 * WN);

    // --- fused activation GEMM (phase-split pipe) ---
    dim3 g3(ROWS / 256, N3 / 128);   // 32 x 24 = 768 blocks
    gemm_pipe<6><<<g3, 512, 0, stream>>>(xbf, W3, bv, nullptr, act3, N3);

    // --- fused phase + chunk sums ---
    phase_scan1_k<<<BATCH * CHUNKS, 256, 0, stream>>>(act3, bp, bck, ms,
                                                      ab, sumr, sumi);
    // --- exclusive chunk prefix ---
    scan_pass2<<<(BATCH * DIM) / 4, 256, 0, stream>>>(sumr, sumi);
    // --- fused scan + retrieved + layernorm ---
    scan3_ln_k<<<BATCH * CHUNKS, 256, 0, stream>>>(ab, act3, bp, bcq, ms,
                                                   sumr, sumi, lng, lnb, normbf);

    // --- out = x + normed @ Wo^T + bo (phase-split pipe) ---
    dim3 gg(ROWS / 256, DIM / 128);  // 32 x 8 = 256 blocks
    gemm_pipe<4><<<gg, 512, 0, stream>>>(normbf, wo_b, bo, x, out, DIM);
}